// Round 1
// baseline (1160.058 us; speedup 1.0000x reference)
//
#include <hip/hip_runtime.h>

#define NTOK 343
#define SCALE 0.2041241452319315f

__device__ __forceinline__ unsigned short f2bf(float f){
  unsigned u = __builtin_bit_cast(unsigned, f);
  u += 0x7fffu + ((u >> 16) & 1u);
  return (unsigned short)(u >> 16);
}
// element t (0..7) of a uint4 holding 8 bf16
__device__ __forceinline__ float bfel(const uint4& q, int t){
  unsigned u = (&q.x)[t >> 1];
  u = (t & 1) ? (u & 0xffff0000u) : (u << 16);
  return __builtin_bit_cast(float, u);
}
__device__ __forceinline__ int region(int g){ return (g < 21) ? 0 : ((g < 25) ? 1 : 2); }

// ---------------- K0: rpb transpose:  rpbT[h][j][r] = table[RPI[r][j]][h] ----------------
__global__ __launch_bounds__(256) void k_rpb(const float* __restrict__ tab, float* __restrict__ rpbT){
  int p = blockIdx.x * 256 + threadIdx.x;
  if (p >= NTOK * NTOK) return;
  int j = p / NTOK, r = p - j * NTOK;
  int r1 = r / 49, rm = r - r1 * 49, r2 = rm / 7, r3 = rm - r2 * 7;
  int j1 = j / 49, jm = j - j1 * 49, j2 = jm / 7, j3 = jm - j2 * 7;
  // faithful-to-source index: both first coords scaled by 13
  int idx = 13 * ((r1 - j1) + (r2 - j2) + 12) + (r3 - j3) + 6;
  #pragma unroll
  for (int h = 0; h < 4; h++)
    rpbT[(size_t)h * 117649 + (size_t)j * 343 + r] = tab[idx * 4 + h];
}

// ---------------- K1: LN1 + shift-gather + QKV GEMM (per window) ----------------
__global__ __launch_bounds__(256) void k_qkv(
    const float* __restrict__ x, const float* __restrict__ n1w, const float* __restrict__ n1b,
    const float* __restrict__ qw, const float* __restrict__ qb,
    unsigned short* __restrict__ qS, unsigned short* __restrict__ kS, unsigned short* __restrict__ vS)
{
  __shared__ __align__(16) unsigned short xwB[NTOK * 96];   // bf16 LN'd window, 65,856 B
  __shared__ __align__(16) unsigned short wtB[288 * 104];   // qkv_w transposed [o][k], 59,904 B
  const int blk = blockIdx.x, b = blk >> 6, wl = blk & 63;
  const int wx = wl >> 4, wy = (wl >> 2) & 3, wz = wl & 3;
  const int tid = threadIdx.x, lane = tid & 63, wv = tid >> 6;

  for (int i = tid; i < 96 * 288; i += 256){
    int k = i / 288, o = i - k * 288;
    wtB[o * 104 + k] = f2bf(qw[i]);
  }
  const float g1 = n1w[lane], h1 = n1b[lane];
  const float g2 = (lane < 32) ? n1w[64 + lane] : 0.f;
  const float h2 = (lane < 32) ? n1b[64 + lane] : 0.f;
  for (int r = wv; r < NTOK; r += 4){
    int tx = r / 49, rm = r - tx * 49, ty = rm / 7, tz = rm - ty * 7;
    int sx = (wx * 7 + tx + 3) % 28, sy = (wy * 7 + ty + 3) % 28, sz = (wz * 7 + tz + 3) % 28;
    const float* xr = x + ((size_t)b * 21952 + ((sx * 28 + sy) * 28 + sz)) * 96;
    float v1 = xr[lane];
    float v2 = (lane < 32) ? xr[64 + lane] : 0.f;
    float s = v1 + v2, sq = v1 * v1 + v2 * v2;
    #pragma unroll
    for (int off = 32; off; off >>= 1){ s += __shfl_xor(s, off); sq += __shfl_xor(sq, off); }
    float mu = s * (1.f / 96.f);
    float rs = rsqrtf(sq * (1.f / 96.f) - mu * mu + 1e-5f);
    xwB[r * 96 + lane] = f2bf((v1 - mu) * rs * g1 + h1);
    if (lane < 32) xwB[r * 96 + 64 + lane] = f2bf((v2 - mu) * rs * g2 + h2);
  }
  __syncthreads();

  const bool j4 = (lane < 32);
  float bj[5], sc[5];
  unsigned short* op[5];
  #pragma unroll
  for (int j = 0; j < 5; j++){
    int o = lane + 64 * j;
    bool valid = (j < 4) || j4;
    if (!valid) o = 0;
    bj[j] = valid ? qb[o] : 0.f;
    int s3 = o / 96, om = o - s3 * 96, hh = om / 24, d = om - hh * 24;
    unsigned short* base = (s3 == 0) ? qS : ((s3 == 1) ? kS : vS);
    op[j] = base + ((size_t)blk * 4 + hh) * 8232 + d;
    sc[j] = (s3 == 0) ? SCALE : 1.f;
  }
  for (int g = wv; g < 43; g += 4){
    const int r0 = g * 8;
    float acc[8][5];
    #pragma unroll
    for (int rr = 0; rr < 8; rr++)
      #pragma unroll
      for (int j = 0; j < 5; j++) acc[rr][j] = 0.f;
    for (int kc = 0; kc < 12; kc++){
      uint4 xq[8], wq[5];
      #pragma unroll
      for (int rr = 0; rr < 8; rr++){
        int r = r0 + rr; if (r > 342) r = 342;
        xq[rr] = *(const uint4*)(xwB + r * 96 + kc * 8);
      }
      #pragma unroll
      for (int j = 0; j < 5; j++){
        int o = lane + 64 * j; if (j == 4 && !j4) o = 0;
        wq[j] = *(const uint4*)(wtB + o * 104 + kc * 8);
      }
      #pragma unroll
      for (int t = 0; t < 8; t++){
        float wf[5];
        #pragma unroll
        for (int j = 0; j < 5; j++) wf[j] = bfel(wq[j], t);
        #pragma unroll
        for (int rr = 0; rr < 8; rr++){
          float xf = bfel(xq[rr], t);
          #pragma unroll
          for (int j = 0; j < 5; j++) acc[rr][j] = fmaf(xf, wf[j], acc[rr][j]);
        }
      }
    }
    #pragma unroll
    for (int rr = 0; rr < 8; rr++){
      int r = r0 + rr; if (r > 342) continue;
      #pragma unroll
      for (int j = 0; j < 5; j++){
        if (j == 4 && !j4) continue;
        op[j][r * 24] = f2bf((acc[rr][j] + bj[j]) * sc[j]);
      }
    }
  }
}

// ---------------- K2: attention (per window, head). Lane owns 1-2 query rows ----------------
__global__ __launch_bounds__(256, 3) void k_attn(
    const unsigned short* __restrict__ qS, const unsigned short* __restrict__ kS,
    const unsigned short* __restrict__ vS, const float* __restrict__ rpbT,
    unsigned short* __restrict__ aO)
{
  __shared__ __align__(16) unsigned short smem[24696];  // q|k|v bf16; q+k reused as fp32 out
  __shared__ int lab[NTOK];
  unsigned short* qB = smem;
  unsigned short* kB = smem + 8232;
  unsigned short* vB = smem + 16464;

  const int blk = blockIdx.x, w = blk >> 2, h = blk & 3;
  const int tid = threadIdx.x;
  const size_t hb = (size_t)blk * 8232;
  {
    const unsigned* qg = (const unsigned*)(qS + hb);
    const unsigned* kg = (const unsigned*)(kS + hb);
    const unsigned* vg = (const unsigned*)(vS + hb);
    unsigned* qd = (unsigned*)qB; unsigned* kd = (unsigned*)kB; unsigned* vd = (unsigned*)vB;
    for (int i = tid; i < 4116; i += 256){ qd[i] = qg[i]; kd[i] = kg[i]; vd[i] = vg[i]; }
  }
  const int wl = w & 63, wx = wl >> 4, wy = (wl >> 2) & 3, wz = wl & 3;
  for (int n = tid; n < NTOK; n += 256){
    int tx = n / 49, nm = n - tx * 49, ty = nm / 7, tz = nm - ty * 7;
    lab[n] = region(wx * 7 + tx) * 9 + region(wy * 7 + ty) * 3 + region(wz * 7 + tz);
  }
  __syncthreads();

  const int r1 = tid;
  const bool has2 = (tid + 256 < NTOK);
  const int r2 = has2 ? (tid + 256) : 0;
  float q1[24], q2[24];
  {
    uint4 a0 = *(const uint4*)(qB + r1 * 24);
    uint4 a1 = *(const uint4*)(qB + r1 * 24 + 8);
    uint4 a2 = *(const uint4*)(qB + r1 * 24 + 16);
    uint4 c0 = *(const uint4*)(qB + r2 * 24);
    uint4 c1 = *(const uint4*)(qB + r2 * 24 + 8);
    uint4 c2 = *(const uint4*)(qB + r2 * 24 + 16);
    #pragma unroll
    for (int t = 0; t < 8; t++){
      q1[t] = bfel(a0, t); q1[8 + t] = bfel(a1, t); q1[16 + t] = bfel(a2, t);
      q2[t] = bfel(c0, t); q2[8 + t] = bfel(c1, t); q2[16 + t] = bfel(c2, t);
    }
  }
  const int l1 = lab[r1], l2 = lab[r2];
  const float* p1 = rpbT + (size_t)h * 117649 + r1;
  const float* p2 = rpbT + (size_t)h * 117649 + r2;
  float sum1 = 0.f, sum2 = 0.f;
  float acc1[24], acc2[24];
  #pragma unroll
  for (int t = 0; t < 24; t++){ acc1[t] = 0.f; acc2[t] = 0.f; }

  for (int j = 0; j < NTOK; j++){
    float bb1 = p1[j * 343];
    float bb2 = p2[j * 343];
    int lj = lab[j];
    uint4 ka = *(const uint4*)(kB + j * 24);
    uint4 kb2 = *(const uint4*)(kB + j * 24 + 8);
    uint4 kc2 = *(const uint4*)(kB + j * 24 + 16);
    float s1 = 0.f, s2 = 0.f;
    #pragma unroll
    for (int t = 0; t < 8; t++){ float f = bfel(ka, t);  s1 = fmaf(q1[t], f, s1);      s2 = fmaf(q2[t], f, s2); }
    #pragma unroll
    for (int t = 0; t < 8; t++){ float f = bfel(kb2, t); s1 = fmaf(q1[8 + t], f, s1);  s2 = fmaf(q2[8 + t], f, s2); }
    #pragma unroll
    for (int t = 0; t < 8; t++){ float f = bfel(kc2, t); s1 = fmaf(q1[16 + t], f, s1); s2 = fmaf(q2[16 + t], f, s2); }
    s1 += bb1 + ((lj == l1) ? 0.f : -100.f);
    s2 += bb2 + ((lj == l2) ? 0.f : -100.f);
    float e1 = __expf(s1);            // scores are O(0.3) or -100 -> exp underflows to 0; no max needed
    float e2 = has2 ? __expf(s2) : 0.f;
    sum1 += e1; sum2 += e2;
    uint4 va = *(const uint4*)(vB + j * 24);
    uint4 vb2 = *(const uint4*)(vB + j * 24 + 8);
    uint4 vc2 = *(const uint4*)(vB + j * 24 + 16);
    #pragma unroll
    for (int t = 0; t < 8; t++){ float f = bfel(va, t);  acc1[t]      = fmaf(e1, f, acc1[t]);      acc2[t]      = fmaf(e2, f, acc2[t]); }
    #pragma unroll
    for (int t = 0; t < 8; t++){ float f = bfel(vb2, t); acc1[8 + t]  = fmaf(e1, f, acc1[8 + t]);  acc2[8 + t]  = fmaf(e2, f, acc2[8 + t]); }
    #pragma unroll
    for (int t = 0; t < 8; t++){ float f = bfel(vc2, t); acc1[16 + t] = fmaf(e1, f, acc1[16 + t]); acc2[16 + t] = fmaf(e2, f, acc2[16 + t]); }
  }
  __syncthreads();
  float* oB = (float*)smem;   // 8232 floats over q+k region (v untouched)
  float i1 = 1.f / sum1;
  #pragma unroll
  for (int t = 0; t < 24; t++) oB[r1 * 24 + t] = acc1[t] * i1;
  if (has2){
    float i2 = 1.f / sum2;
    #pragma unroll
    for (int t = 0; t < 24; t++) oB[r2 * 24 + t] = acc2[t] * i2;
  }
  __syncthreads();
  unsigned short* dst = aO + (size_t)w * 32928 + h * 24;
  for (int i = tid; i < 8232; i += 256){
    int row = i / 24, c = i - row * 24;
    dst[row * 96 + c] = f2bf(oB[i]);
  }
}

// ---------------- K3: proj + window-reverse + un-shift + residual -> d_out (= x2) ----------------
__global__ __launch_bounds__(256) void k_proj(
    const unsigned short* __restrict__ aO, const float* __restrict__ pw, const float* __restrict__ pb,
    const float* __restrict__ x, float* __restrict__ out)
{
  __shared__ __align__(16) unsigned short aB[NTOK * 96];
  __shared__ __align__(16) unsigned short ptB[96 * 104];
  const int blk = blockIdx.x, b = blk >> 6, wl = blk & 63;
  const int wx = wl >> 4, wy = (wl >> 2) & 3, wz = wl & 3;
  const int tid = threadIdx.x, lane = tid & 63, wv = tid >> 6;
  {
    const unsigned* ag = (const unsigned*)(aO + (size_t)blk * 32928);
    unsigned* ad = (unsigned*)aB;
    for (int i = tid; i < 16464; i += 256) ad[i] = ag[i];
  }
  for (int i = tid; i < 96 * 96; i += 256){
    int k = i / 96, o = i - k * 96;
    ptB[o * 104 + k] = f2bf(pw[i]);
  }
  __syncthreads();
  const bool j1v = (lane < 32);
  const int o0 = lane, o1 = 64 + (lane & 31);
  const float pb0 = pb[o0], pb1 = pb[o1];
  for (int g = wv; g < 43; g += 4){
    const int r0 = g * 8;
    float acc[8][2];
    #pragma unroll
    for (int rr = 0; rr < 8; rr++){ acc[rr][0] = 0.f; acc[rr][1] = 0.f; }
    for (int kc = 0; kc < 12; kc++){
      uint4 xq[8];
      #pragma unroll
      for (int rr = 0; rr < 8; rr++){
        int r = r0 + rr; if (r > 342) r = 342;
        xq[rr] = *(const uint4*)(aB + r * 96 + kc * 8);
      }
      uint4 w0 = *(const uint4*)(ptB + o0 * 104 + kc * 8);
      uint4 w1 = *(const uint4*)(ptB + o1 * 104 + kc * 8);
      #pragma unroll
      for (int t = 0; t < 8; t++){
        float f0 = bfel(w0, t), f1 = bfel(w1, t);
        #pragma unroll
        for (int rr = 0; rr < 8; rr++){
          float xf = bfel(xq[rr], t);
          acc[rr][0] = fmaf(xf, f0, acc[rr][0]);
          acc[rr][1] = fmaf(xf, f1, acc[rr][1]);
        }
      }
    }
    #pragma unroll
    for (int rr = 0; rr < 8; rr++){
      int r = r0 + rr; if (r > 342) continue;
      int tx = r / 49, rm = r - tx * 49, ty = rm / 7, tz = rm - ty * 7;
      int sx = (wx * 7 + tx + 3) % 28, sy = (wy * 7 + ty + 3) % 28, sz = (wz * 7 + tz + 3) % 28;
      size_t oi = ((size_t)b * 21952 + ((sx * 28 + sy) * 28 + sz)) * 96;
      out[oi + o0] = acc[rr][0] + pb0 + x[oi + o0];
      if (j1v) out[oi + o1] = acc[rr][1] + pb1 + x[oi + o1];
    }
  }
}

// ---------------- K4: LN2 + fc1 + GeLU + fc2 + residual, in-place on d_out ----------------
__global__ __launch_bounds__(256) void k_mlp(
    float* __restrict__ io, const float* __restrict__ n2w, const float* __restrict__ n2b,
    const float* __restrict__ w1g, const float* __restrict__ b1g,
    const float* __restrict__ w2g, const float* __restrict__ b2g)
{
  __shared__ __align__(16) unsigned short xnB[64 * 96];    // 12,288 B
  __shared__ __align__(16) unsigned short hB[64 * 392];    // 50,176 B (stride 392 keeps 16B align)
  __shared__ __align__(16) unsigned short wB[384 * 104];   // 79,872 B, reused for fc2 [96][392]
  const size_t row0 = (size_t)blockIdx.x * 64;
  const int tid = threadIdx.x, lane = tid & 63, wv = tid >> 6;

  for (int i = tid; i < 96 * 384; i += 256){
    int k = i / 384, c = i - k * 384;
    wB[c * 104 + k] = f2bf(w1g[i]);
  }
  const float g1 = n2w[lane], h1 = n2b[lane];
  const float g2 = (lane < 32) ? n2w[64 + lane] : 0.f;
  const float h2 = (lane < 32) ? n2b[64 + lane] : 0.f;
  for (int r = wv; r < 64; r += 4){
    const float* xr = io + (row0 + r) * 96;
    float v1 = xr[lane], v2 = (lane < 32) ? xr[64 + lane] : 0.f;
    float s = v1 + v2, sq = v1 * v1 + v2 * v2;
    #pragma unroll
    for (int off = 32; off; off >>= 1){ s += __shfl_xor(s, off); sq += __shfl_xor(sq, off); }
    float mu = s * (1.f / 96.f);
    float rs = rsqrtf(sq * (1.f / 96.f) - mu * mu + 1e-5f);
    xnB[r * 96 + lane] = f2bf((v1 - mu) * rs * g1 + h1);
    if (lane < 32) xnB[r * 96 + 64 + lane] = f2bf((v2 - mu) * rs * g2 + h2);
  }
  __syncthreads();

  // fc1 + gelu
  float fb[6];
  #pragma unroll
  for (int j = 0; j < 6; j++) fb[j] = b1g[lane + 64 * j];
  for (int g = wv; g < 8; g += 4){
    const int r0 = g * 8;
    float acc[8][6];
    #pragma unroll
    for (int rr = 0; rr < 8; rr++)
      #pragma unroll
      for (int j = 0; j < 6; j++) acc[rr][j] = 0.f;
    for (int kc = 0; kc < 12; kc++){
      uint4 xq[8], wq[6];
      #pragma unroll
      for (int rr = 0; rr < 8; rr++) xq[rr] = *(const uint4*)(xnB + (r0 + rr) * 96 + kc * 8);
      #pragma unroll
      for (int j = 0; j < 6; j++) wq[j] = *(const uint4*)(wB + (lane + 64 * j) * 104 + kc * 8);
      #pragma unroll
      for (int t = 0; t < 8; t++){
        float wf[6];
        #pragma unroll
        for (int j = 0; j < 6; j++) wf[j] = bfel(wq[j], t);
        #pragma unroll
        for (int rr = 0; rr < 8; rr++){
          float xf = bfel(xq[rr], t);
          #pragma unroll
          for (int j = 0; j < 6; j++) acc[rr][j] = fmaf(xf, wf[j], acc[rr][j]);
        }
      }
    }
    #pragma unroll
    for (int rr = 0; rr < 8; rr++)
      #pragma unroll
      for (int j = 0; j < 6; j++){
        float v = acc[rr][j] + fb[j];
        float ge = 0.5f * v * (1.f + erff(v * 0.70710678118654752f));
        hB[(r0 + rr) * 392 + lane + 64 * j] = f2bf(ge);
      }
  }
  __syncthreads();
  for (int i = tid; i < 384 * 96; i += 256){
    int k = i / 96, o = i - k * 96;
    wB[o * 392 + k] = f2bf(w2g[i]);
  }
  __syncthreads();

  // fc2 + residual
  const bool j1v = (lane < 32);
  const int o0 = lane, o1 = 64 + (lane & 31);
  const float c0 = b2g[o0], c1 = b2g[o1];
  for (int g = wv; g < 8; g += 4){
    const int r0 = g * 8;
    float acc[8][2];
    #pragma unroll
    for (int rr = 0; rr < 8; rr++){ acc[rr][0] = 0.f; acc[rr][1] = 0.f; }
    for (int kc = 0; kc < 48; kc++){
      uint4 xq[8];
      #pragma unroll
      for (int rr = 0; rr < 8; rr++) xq[rr] = *(const uint4*)(hB + (r0 + rr) * 392 + kc * 8);
      uint4 wa = *(const uint4*)(wB + o0 * 392 + kc * 8);
      uint4 wb = *(const uint4*)(wB + o1 * 392 + kc * 8);
      #pragma unroll
      for (int t = 0; t < 8; t++){
        float f0 = bfel(wa, t), f1 = bfel(wb, t);
        #pragma unroll
        for (int rr = 0; rr < 8; rr++){
          float xf = bfel(xq[rr], t);
          acc[rr][0] = fmaf(xf, f0, acc[rr][0]);
          acc[rr][1] = fmaf(xf, f1, acc[rr][1]);
        }
      }
    }
    #pragma unroll
    for (int rr = 0; rr < 8; rr++){
      float* orow = io + (row0 + r0 + rr) * 96;
      orow[o0] += acc[rr][0] + c0;
      if (j1v) orow[o1] += acc[rr][1] + c1;
    }
  }
}

extern "C" void kernel_launch(void* const* d_in, const int* in_sizes, int n_in,
                              void* d_out, int out_size, void* d_ws, size_t ws_size,
                              hipStream_t stream)
{
  const float* x      = (const float*)d_in[0];
  const float* n1w    = (const float*)d_in[1];
  const float* n1b    = (const float*)d_in[2];
  const float* qkvw   = (const float*)d_in[3];
  const float* qkvb   = (const float*)d_in[4];
  const float* rpbtab = (const float*)d_in[5];
  const float* projw  = (const float*)d_in[6];
  const float* projb  = (const float*)d_in[7];
  const float* n2w    = (const float*)d_in[8];
  const float* n2b    = (const float*)d_in[9];
  const float* fc1w   = (const float*)d_in[10];
  const float* fc1b   = (const float*)d_in[11];
  const float* fc2w   = (const float*)d_in[12];
  const float* fc2b   = (const float*)d_in[13];
  float* out = (float*)d_out;

  // workspace: q/k/v/attn_out in bf16, rpbT in fp32  (total ~69.3 MB)
  unsigned short* qS = (unsigned short*)d_ws;
  unsigned short* kS = qS + 8429568;
  unsigned short* vS = kS + 8429568;
  unsigned short* aO = vS + 8429568;
  float* rpbT = (float*)(aO + 8429568);

  k_rpb <<<dim3(460),  dim3(256), 0, stream>>>(rpbtab, rpbT);
  k_qkv <<<dim3(256),  dim3(256), 0, stream>>>(x, n1w, n1b, qkvw, qkvb, qS, kS, vS);
  k_attn<<<dim3(1024), dim3(256), 0, stream>>>(qS, kS, vS, rpbT, aO);
  k_proj<<<dim3(256),  dim3(256), 0, stream>>>(aO, projw, projb, x, out);
  k_mlp <<<dim3(1372), dim3(256), 0, stream>>>(out, n2w, n2b, fc1w, fc1b, fc2w, fc2b);
}

// Round 2
// 748.877 us; speedup vs baseline: 1.5491x; 1.5491x over previous
//
#include <hip/hip_runtime.h>

#define NTOK 343
#define SCALE 0.2041241452319315f

typedef __attribute__((ext_vector_type(8))) short bf16x8;
typedef __attribute__((ext_vector_type(4))) float f32x4;

__device__ __forceinline__ unsigned short f2bf(float f){
  unsigned u = __builtin_bit_cast(unsigned, f);
  u += 0x7fffu + ((u >> 16) & 1u);
  return (unsigned short)(u >> 16);
}
// element t (0..7) of a uint4 holding 8 bf16
__device__ __forceinline__ float bfel(const uint4& q, int t){
  unsigned u = (&q.x)[t >> 1];
  u = (t & 1) ? (u & 0xffff0000u) : (u << 16);
  return __builtin_bit_cast(float, u);
}
__device__ __forceinline__ int region(int g){ return (g < 21) ? 0 : ((g < 25) ? 1 : 2); }

// ---------------- K0: rpb transpose:  rpbT[h][j][r] = table[RPI[r][j]][h] ----------------
__global__ __launch_bounds__(256) void k_rpb(const float* __restrict__ tab, float* __restrict__ rpbT){
  int p = blockIdx.x * 256 + threadIdx.x;
  if (p >= NTOK * NTOK) return;
  int j = p / NTOK, r = p - j * NTOK;
  int r1 = r / 49, rm = r - r1 * 49, r2 = rm / 7, r3 = rm - r2 * 7;
  int j1 = j / 49, jm = j - j1 * 49, j2 = jm / 7, j3 = jm - j2 * 7;
  int idx = 13 * ((r1 - j1) + (r2 - j2) + 12) + (r3 - j3) + 6;
  #pragma unroll
  for (int h = 0; h < 4; h++)
    rpbT[(size_t)h * 117649 + (size_t)j * 343 + r] = tab[idx * 4 + h];
}

// ---------------- K1: LN1 + shift-gather + QKV GEMM (per window) ----------------
__global__ __launch_bounds__(256) void k_qkv(
    const float* __restrict__ x, const float* __restrict__ n1w, const float* __restrict__ n1b,
    const float* __restrict__ qw, const float* __restrict__ qb,
    unsigned short* __restrict__ qS, unsigned short* __restrict__ kS, unsigned short* __restrict__ vS)
{
  __shared__ __align__(16) unsigned short xwB[NTOK * 96];
  __shared__ __align__(16) unsigned short wtB[288 * 104];
  const int blk = blockIdx.x, b = blk >> 6, wl = blk & 63;
  const int wx = wl >> 4, wy = (wl >> 2) & 3, wz = wl & 3;
  const int tid = threadIdx.x, lane = tid & 63, wv = tid >> 6;

  for (int i = tid; i < 96 * 288; i += 256){
    int k = i / 288, o = i - k * 288;
    wtB[o * 104 + k] = f2bf(qw[i]);
  }
  const float g1 = n1w[lane], h1 = n1b[lane];
  const float g2 = (lane < 32) ? n1w[64 + lane] : 0.f;
  const float h2 = (lane < 32) ? n1b[64 + lane] : 0.f;
  for (int r = wv; r < NTOK; r += 4){
    int tx = r / 49, rm = r - tx * 49, ty = rm / 7, tz = rm - ty * 7;
    int sx = (wx * 7 + tx + 3) % 28, sy = (wy * 7 + ty + 3) % 28, sz = (wz * 7 + tz + 3) % 28;
    const float* xr = x + ((size_t)b * 21952 + ((sx * 28 + sy) * 28 + sz)) * 96;
    float v1 = xr[lane];
    float v2 = (lane < 32) ? xr[64 + lane] : 0.f;
    float s = v1 + v2, sq = v1 * v1 + v2 * v2;
    #pragma unroll
    for (int off = 32; off; off >>= 1){ s += __shfl_xor(s, off); sq += __shfl_xor(sq, off); }
    float mu = s * (1.f / 96.f);
    float rs = rsqrtf(sq * (1.f / 96.f) - mu * mu + 1e-5f);
    xwB[r * 96 + lane] = f2bf((v1 - mu) * rs * g1 + h1);
    if (lane < 32) xwB[r * 96 + 64 + lane] = f2bf((v2 - mu) * rs * g2 + h2);
  }
  __syncthreads();

  const bool j4 = (lane < 32);
  float bj[5], sc[5];
  unsigned short* op[5];
  #pragma unroll
  for (int j = 0; j < 5; j++){
    int o = lane + 64 * j;
    bool valid = (j < 4) || j4;
    if (!valid) o = 0;
    bj[j] = valid ? qb[o] : 0.f;
    int s3 = o / 96, om = o - s3 * 96, hh = om / 24, d = om - hh * 24;
    unsigned short* base = (s3 == 0) ? qS : ((s3 == 1) ? kS : vS);
    op[j] = base + ((size_t)blk * 4 + hh) * 8232 + d;
    sc[j] = (s3 == 0) ? SCALE : 1.f;
  }
  for (int g = wv; g < 43; g += 4){
    const int r0 = g * 8;
    float acc[8][5];
    #pragma unroll
    for (int rr = 0; rr < 8; rr++)
      #pragma unroll
      for (int j = 0; j < 5; j++) acc[rr][j] = 0.f;
    for (int kc = 0; kc < 12; kc++){
      uint4 xq[8], wq[5];
      #pragma unroll
      for (int rr = 0; rr < 8; rr++){
        int r = r0 + rr; if (r > 342) r = 342;
        xq[rr] = *(const uint4*)(xwB + r * 96 + kc * 8);
      }
      #pragma unroll
      for (int j = 0; j < 5; j++){
        int o = lane + 64 * j; if (j == 4 && !j4) o = 0;
        wq[j] = *(const uint4*)(wtB + o * 104 + kc * 8);
      }
      #pragma unroll
      for (int t = 0; t < 8; t++){
        float wf[5];
        #pragma unroll
        for (int j = 0; j < 5; j++) wf[j] = bfel(wq[j], t);
        #pragma unroll
        for (int rr = 0; rr < 8; rr++){
          float xf = bfel(xq[rr], t);
          #pragma unroll
          for (int j = 0; j < 5; j++) acc[rr][j] = fmaf(xf, wf[j], acc[rr][j]);
        }
      }
    }
    #pragma unroll
    for (int rr = 0; rr < 8; rr++){
      int r = r0 + rr; if (r > 342) continue;
      #pragma unroll
      for (int j = 0; j < 5; j++){
        if (j == 4 && !j4) continue;
        op[j][r * 24] = f2bf((acc[rr][j] + bj[j]) * sc[j]);
      }
    }
  }
}

// ---------------- K2: attention (per window, head) ----------------
__global__ __launch_bounds__(256, 3) void k_attn(
    const unsigned short* __restrict__ qS, const unsigned short* __restrict__ kS,
    const unsigned short* __restrict__ vS, const float* __restrict__ rpbT,
    unsigned short* __restrict__ aO)
{
  __shared__ __align__(16) unsigned short smem[24696];
  __shared__ int lab[NTOK];
  unsigned short* qB = smem;
  unsigned short* kB = smem + 8232;
  unsigned short* vB = smem + 16464;

  const int blk = blockIdx.x, w = blk >> 2, h = blk & 3;
  const int tid = threadIdx.x;
  const size_t hb = (size_t)blk * 8232;
  {
    const unsigned* qg = (const unsigned*)(qS + hb);
    const unsigned* kg = (const unsigned*)(kS + hb);
    const unsigned* vg = (const unsigned*)(vS + hb);
    unsigned* qd = (unsigned*)qB; unsigned* kd = (unsigned*)kB; unsigned* vd = (unsigned*)vB;
    for (int i = tid; i < 4116; i += 256){ qd[i] = qg[i]; kd[i] = kg[i]; vd[i] = vg[i]; }
  }
  const int wl = w & 63, wx = wl >> 4, wy = (wl >> 2) & 3, wz = wl & 3;
  for (int n = tid; n < NTOK; n += 256){
    int tx = n / 49, nm = n - tx * 49, ty = nm / 7, tz = nm - ty * 7;
    lab[n] = region(wx * 7 + tx) * 9 + region(wy * 7 + ty) * 3 + region(wz * 7 + tz);
  }
  __syncthreads();

  const int r1 = tid;
  const bool has2 = (tid + 256 < NTOK);
  const int r2 = has2 ? (tid + 256) : 0;
  float q1[24], q2[24];
  {
    uint4 a0 = *(const uint4*)(qB + r1 * 24);
    uint4 a1 = *(const uint4*)(qB + r1 * 24 + 8);
    uint4 a2 = *(const uint4*)(qB + r1 * 24 + 16);
    uint4 c0 = *(const uint4*)(qB + r2 * 24);
    uint4 c1 = *(const uint4*)(qB + r2 * 24 + 8);
    uint4 c2 = *(const uint4*)(qB + r2 * 24 + 16);
    #pragma unroll
    for (int t = 0; t < 8; t++){
      q1[t] = bfel(a0, t); q1[8 + t] = bfel(a1, t); q1[16 + t] = bfel(a2, t);
      q2[t] = bfel(c0, t); q2[8 + t] = bfel(c1, t); q2[16 + t] = bfel(c2, t);
    }
  }
  const int l1 = lab[r1], l2 = lab[r2];
  const float* p1 = rpbT + (size_t)h * 117649 + r1;
  const float* p2 = rpbT + (size_t)h * 117649 + r2;
  float sum1 = 0.f, sum2 = 0.f;
  float acc1[24], acc2[24];
  #pragma unroll
  for (int t = 0; t < 24; t++){ acc1[t] = 0.f; acc2[t] = 0.f; }

  for (int j = 0; j < NTOK; j++){
    float bb1 = p1[j * 343];
    float bb2 = p2[j * 343];
    int lj = lab[j];
    uint4 ka = *(const uint4*)(kB + j * 24);
    uint4 kb2 = *(const uint4*)(kB + j * 24 + 8);
    uint4 kc2 = *(const uint4*)(kB + j * 24 + 16);
    float s1 = 0.f, s2 = 0.f;
    #pragma unroll
    for (int t = 0; t < 8; t++){ float f = bfel(ka, t);  s1 = fmaf(q1[t], f, s1);      s2 = fmaf(q2[t], f, s2); }
    #pragma unroll
    for (int t = 0; t < 8; t++){ float f = bfel(kb2, t); s1 = fmaf(q1[8 + t], f, s1);  s2 = fmaf(q2[8 + t], f, s2); }
    #pragma unroll
    for (int t = 0; t < 8; t++){ float f = bfel(kc2, t); s1 = fmaf(q1[16 + t], f, s1); s2 = fmaf(q2[16 + t], f, s2); }
    s1 += bb1 + ((lj == l1) ? 0.f : -100.f);
    s2 += bb2 + ((lj == l2) ? 0.f : -100.f);
    float e1 = __expf(s1);
    float e2 = has2 ? __expf(s2) : 0.f;
    sum1 += e1; sum2 += e2;
    uint4 va = *(const uint4*)(vB + j * 24);
    uint4 vb2 = *(const uint4*)(vB + j * 24 + 8);
    uint4 vc2 = *(const uint4*)(vB + j * 24 + 16);
    #pragma unroll
    for (int t = 0; t < 8; t++){ float f = bfel(va, t);  acc1[t]      = fmaf(e1, f, acc1[t]);      acc2[t]      = fmaf(e2, f, acc2[t]); }
    #pragma unroll
    for (int t = 0; t < 8; t++){ float f = bfel(vb2, t); acc1[8 + t]  = fmaf(e1, f, acc1[8 + t]);  acc2[8 + t]  = fmaf(e2, f, acc2[8 + t]); }
    #pragma unroll
    for (int t = 0; t < 8; t++){ float f = bfel(vc2, t); acc1[16 + t] = fmaf(e1, f, acc1[16 + t]); acc2[16 + t] = fmaf(e2, f, acc2[16 + t]); }
  }
  __syncthreads();
  float* oB = (float*)smem;
  float i1 = 1.f / sum1;
  #pragma unroll
  for (int t = 0; t < 24; t++) oB[r1 * 24 + t] = acc1[t] * i1;
  if (has2){
    float i2 = 1.f / sum2;
    #pragma unroll
    for (int t = 0; t < 24; t++) oB[r2 * 24 + t] = acc2[t] * i2;
  }
  __syncthreads();
  unsigned short* dst = aO + (size_t)w * 32928 + h * 24;
  for (int i = tid; i < 8232; i += 256){
    int row = i / 24, c = i - row * 24;
    dst[row * 96 + c] = f2bf(oB[i]);
  }
}

// ---------------- K3: proj + window-reverse + un-shift + residual -> d_out ----------------
__global__ __launch_bounds__(256) void k_proj(
    const unsigned short* __restrict__ aO, const float* __restrict__ pw, const float* __restrict__ pb,
    const float* __restrict__ x, float* __restrict__ out)
{
  __shared__ __align__(16) unsigned short aB[NTOK * 96];
  __shared__ __align__(16) unsigned short ptB[96 * 104];
  const int blk = blockIdx.x, b = blk >> 6, wl = blk & 63;
  const int wx = wl >> 4, wy = (wl >> 2) & 3, wz = wl & 3;
  const int tid = threadIdx.x, lane = tid & 63, wv = tid >> 6;
  {
    const unsigned* ag = (const unsigned*)(aO + (size_t)blk * 32928);
    unsigned* ad = (unsigned*)aB;
    for (int i = tid; i < 16464; i += 256) ad[i] = ag[i];
  }
  for (int i = tid; i < 96 * 96; i += 256){
    int k = i / 96, o = i - k * 96;
    ptB[o * 104 + k] = f2bf(pw[i]);
  }
  __syncthreads();
  const bool j1v = (lane < 32);
  const int o0 = lane, o1 = 64 + (lane & 31);
  const float pb0 = pb[o0], pb1 = pb[o1];
  for (int g = wv; g < 43; g += 4){
    const int r0 = g * 8;
    float acc[8][2];
    #pragma unroll
    for (int rr = 0; rr < 8; rr++){ acc[rr][0] = 0.f; acc[rr][1] = 0.f; }
    for (int kc = 0; kc < 12; kc++){
      uint4 xq[8];
      #pragma unroll
      for (int rr = 0; rr < 8; rr++){
        int r = r0 + rr; if (r > 342) r = 342;
        xq[rr] = *(const uint4*)(aB + r * 96 + kc * 8);
      }
      uint4 w0 = *(const uint4*)(ptB + o0 * 104 + kc * 8);
      uint4 w1 = *(const uint4*)(ptB + o1 * 104 + kc * 8);
      #pragma unroll
      for (int t = 0; t < 8; t++){
        float f0 = bfel(w0, t), f1 = bfel(w1, t);
        #pragma unroll
        for (int rr = 0; rr < 8; rr++){
          float xf = bfel(xq[rr], t);
          acc[rr][0] = fmaf(xf, f0, acc[rr][0]);
          acc[rr][1] = fmaf(xf, f1, acc[rr][1]);
        }
      }
    }
    #pragma unroll
    for (int rr = 0; rr < 8; rr++){
      int r = r0 + rr; if (r > 342) continue;
      int tx = r / 49, rm = r - tx * 49, ty = rm / 7, tz = rm - ty * 7;
      int sx = (wx * 7 + tx + 3) % 28, sy = (wy * 7 + ty + 3) % 28, sz = (wz * 7 + tz + 3) % 28;
      size_t oi = ((size_t)b * 21952 + ((sx * 28 + sy) * 28 + sz)) * 96;
      out[oi + o0] = acc[rr][0] + pb0 + x[oi + o0];
      if (j1v) out[oi + o1] = acc[rr][1] + pb1 + x[oi + o1];
    }
  }
}

// ---------------- K-prep: fc1/fc2 weights -> bf16 MFMA A-fragment layout ----------------
// w1F[((mt*12+q)*16+m)*8+e] = w1[k=q*8+e][o=mt*16+m]   (96x384)
// w2F[((omt*48+q)*16+m)*8+e] = w2[k=q*8+e][o=omt*16+m] (384x96)
__global__ __launch_bounds__(256) void k_wprep(
    const float* __restrict__ w1g, const float* __restrict__ w2g,
    unsigned short* __restrict__ w1F, unsigned short* __restrict__ w2F)
{
  int p = blockIdx.x * 256 + threadIdx.x;
  if (p < 36864){
    int e = p & 7, m = (p >> 3) & 15, cell = p >> 7;
    int mt = cell / 12, q = cell - mt * 12;
    w1F[p] = f2bf(w1g[(q * 8 + e) * 384 + mt * 16 + m]);
  } else if (p < 73728){
    int p2 = p - 36864;
    int e = p2 & 7, m = (p2 >> 3) & 15, cell = p2 >> 7;
    int omt = cell / 48, q = cell - omt * 48;
    w2F[p2] = f2bf(w2g[(q * 8 + e) * 96 + omt * 16 + m]);
  }
}

// ---------------- K4: MFMA MLP: LN2 + fc1 + GeLU + fc2 + residual (32 rows/block) ----------------
// Orientation: D[m=channel][n=token]. A = weights (frag layout, global), B = activations (LDS frags).
__global__ __launch_bounds__(256, 4) void k_mlp(
    float* __restrict__ io, const float* __restrict__ n2w, const float* __restrict__ n2b,
    const unsigned short* __restrict__ w1F, const float* __restrict__ b1g,
    const unsigned short* __restrict__ w2F, const float* __restrict__ b2g)
{
  __shared__ __align__(16) unsigned short xnF[2 * 12 * 16 * 8];  // [nt][q][n][e]  6144 B
  __shared__ __align__(16) unsigned short hF[2 * 48 * 16 * 8];   // [nt][q][n][e] 24576 B
  const int tid = threadIdx.x, lane = tid & 63, wv = tid >> 6;
  const size_t row0 = (size_t)blockIdx.x * 32;

  // LN2 over the block's 32 rows -> xnF fragment layout (bf16)
  const float g1 = n2w[lane], c1 = n2b[lane];
  const float g2 = (lane < 32) ? n2w[64 + lane] : 0.f;
  const float c2 = (lane < 32) ? n2b[64 + lane] : 0.f;
  for (int r = wv; r < 32; r += 4){
    const float* xr = io + (row0 + r) * 96;
    float v1 = xr[lane], v2 = (lane < 32) ? xr[64 + lane] : 0.f;
    float s = v1 + v2, sq = v1 * v1 + v2 * v2;
    #pragma unroll
    for (int off = 32; off; off >>= 1){ s += __shfl_xor(s, off); sq += __shfl_xor(sq, off); }
    float mu = s * (1.f / 96.f);
    float rs = rsqrtf(sq * (1.f / 96.f) - mu * mu + 1e-5f);
    int nt = r >> 4, n = r & 15;
    int c = lane;
    xnF[((nt * 12 + (c >> 3)) * 16 + n) * 8 + (c & 7)] = f2bf((v1 - mu) * rs * g1 + c1);
    if (lane < 32){
      int cc = 64 + lane;
      xnF[((nt * 12 + (cc >> 3)) * 16 + n) * 8 + (cc & 7)] = f2bf((v2 - mu) * rs * g2 + c2);
    }
  }
  __syncthreads();

  const int h = lane & 15, q = lane >> 4;   // n-within-tile, k-quad
  const int nt = wv & 1, mh = wv >> 1;      // token tile, M-half

  // ---- fc1: this wave: 12 m-tiles (192 hidden ch), 16 tokens, K=96 ----
  f32x4 acc[12];
  #pragma unroll
  for (int mt = 0; mt < 12; mt++){
    int o0 = (mh * 12 + mt) * 16 + 4 * q;
    float4 bv = *(const float4*)(b1g + o0);
    acc[mt][0] = bv.x; acc[mt][1] = bv.y; acc[mt][2] = bv.z; acc[mt][3] = bv.w;
  }
  for (int ks = 0; ks < 3; ks++){
    bf16x8 bfr = *(const bf16x8*)(xnF + ((nt * 12 + ks * 4 + q) * 16 + h) * 8);
    #pragma unroll
    for (int mt = 0; mt < 12; mt++){
      bf16x8 afr = *(const bf16x8*)(w1F + (((mh * 12 + mt) * 12 + ks * 4 + q) * 16 + h) * 8);
      acc[mt] = __builtin_amdgcn_mfma_f32_16x16x32_bf16(afr, bfr, acc[mt], 0, 0, 0);
    }
  }
  // GeLU (exact, erf) + pack 4 bf16 -> hF in fc2-B-fragment layout
  #pragma unroll
  for (int mt = 0; mt < 12; mt++){
    int o0 = (mh * 12 + mt) * 16 + 4 * q;
    unsigned short pk[4];
    #pragma unroll
    for (int rg = 0; rg < 4; rg++){
      float v = acc[mt][rg];
      pk[rg] = f2bf(0.5f * v * (1.f + erff(v * 0.70710678118654752f)));
    }
    unsigned short* d = hF + ((nt * 48 + (o0 >> 3)) * 16 + h) * 8 + (o0 & 7);
    uint2 pkv; pkv.x = (unsigned)pk[0] | ((unsigned)pk[1] << 16);
    pkv.y = (unsigned)pk[2] | ((unsigned)pk[3] << 16);
    *(uint2*)d = pkv;
  }
  __syncthreads();

  // ---- fc2: this wave: 3 m-tiles (48 out ch), 16 tokens, K=384 ----
  f32x4 acc2[3];
  #pragma unroll
  for (int mt = 0; mt < 3; mt++){
    int o0 = (mh * 3 + mt) * 16 + 4 * q;
    float4 bv = *(const float4*)(b2g + o0);
    acc2[mt][0] = bv.x; acc2[mt][1] = bv.y; acc2[mt][2] = bv.z; acc2[mt][3] = bv.w;
  }
  for (int ks = 0; ks < 12; ks++){
    bf16x8 bfr = *(const bf16x8*)(hF + ((nt * 48 + ks * 4 + q) * 16 + h) * 8);
    #pragma unroll
    for (int mt = 0; mt < 3; mt++){
      bf16x8 afr = *(const bf16x8*)(w2F + (((mh * 3 + mt) * 48 + ks * 4 + q) * 16 + h) * 8);
      acc2[mt] = __builtin_amdgcn_mfma_f32_16x16x32_bf16(afr, bfr, acc2[mt], 0, 0, 0);
    }
  }
  // epilogue: residual add, coalesced float4 per (row, 16-ch chunk)
  float* orow = io + (row0 + nt * 16 + h) * 96;
  #pragma unroll
  for (int mt = 0; mt < 3; mt++){
    int o0 = (mh * 3 + mt) * 16 + 4 * q;
    float4 cur = *(const float4*)(orow + o0);
    cur.x += acc2[mt][0]; cur.y += acc2[mt][1]; cur.z += acc2[mt][2]; cur.w += acc2[mt][3];
    *(float4*)(orow + o0) = cur;
  }
}

extern "C" void kernel_launch(void* const* d_in, const int* in_sizes, int n_in,
                              void* d_out, int out_size, void* d_ws, size_t ws_size,
                              hipStream_t stream)
{
  const float* x      = (const float*)d_in[0];
  const float* n1w    = (const float*)d_in[1];
  const float* n1b    = (const float*)d_in[2];
  const float* qkvw   = (const float*)d_in[3];
  const float* qkvb   = (const float*)d_in[4];
  const float* rpbtab = (const float*)d_in[5];
  const float* projw  = (const float*)d_in[6];
  const float* projb  = (const float*)d_in[7];
  const float* n2w    = (const float*)d_in[8];
  const float* n2b    = (const float*)d_in[9];
  const float* fc1w   = (const float*)d_in[10];
  const float* fc1b   = (const float*)d_in[11];
  const float* fc2w   = (const float*)d_in[12];
  const float* fc2b   = (const float*)d_in[13];
  float* out = (float*)d_out;

  unsigned short* qS = (unsigned short*)d_ws;
  unsigned short* kS = qS + 8429568;
  unsigned short* vS = kS + 8429568;
  unsigned short* aO = vS + 8429568;
  float* rpbT = (float*)(aO + 8429568);
  // fc weights in fragment layout: alias the qS region (only live until k_attn completes;
  // k_wprep runs after k_attn in stream order, before k_mlp reads them)
  unsigned short* w1F = qS;
  unsigned short* w2F = qS + 36864;

  k_rpb  <<<dim3(460),  dim3(256), 0, stream>>>(rpbtab, rpbT);
  k_qkv  <<<dim3(256),  dim3(256), 0, stream>>>(x, n1w, n1b, qkvw, qkvb, qS, kS, vS);
  k_attn <<<dim3(1024), dim3(256), 0, stream>>>(qS, kS, vS, rpbT, aO);
  k_wprep<<<dim3(288),  dim3(256), 0, stream>>>(fc1w, fc2w, w1F, w2F);
  k_proj <<<dim3(256),  dim3(256), 0, stream>>>(aO, projw, projb, x, out);
  k_mlp  <<<dim3(2744), dim3(256), 0, stream>>>(out, n2w, n2b, w1F, fc1b, w2F, fc2b);
}

// Round 3
// 520.460 us; speedup vs baseline: 2.2289x; 1.4389x over previous
//
#include <hip/hip_runtime.h>

#define NTOK 343
#define NP   352
#define SCALE 0.2041241452319315f
#define VSTR 360   // VT LDS row stride (halves): 720B rows -> 16B-aligned b128, 2-way banks
#define PSTR 40    // P buf row stride (halves): 80B rows -> 16B-aligned b128

typedef __attribute__((ext_vector_type(8))) short bf16x8;
typedef __attribute__((ext_vector_type(4))) float f32x4;

__device__ __forceinline__ unsigned short f2bf(float f){
  unsigned u = __builtin_bit_cast(unsigned, f);
  u += 0x7fffu + ((u >> 16) & 1u);
  return (unsigned short)(u >> 16);
}
// element t (0..7) of a uint4 holding 8 bf16
__device__ __forceinline__ float bfel(const uint4& q, int t){
  unsigned u = (&q.x)[t >> 1];
  u = (t & 1) ? (u & 0xffff0000u) : (u << 16);
  return __builtin_bit_cast(float, u);
}
// pack two floats -> 2 bf16 (round-half-up via +0x8000, then byte-perm the high halves)
__device__ __forceinline__ unsigned pk2(float a, float b){
  unsigned ua = __builtin_bit_cast(unsigned, a) + 0x8000u;
  unsigned ub = __builtin_bit_cast(unsigned, b) + 0x8000u;
  return __builtin_amdgcn_perm(ub, ua, 0x07060302u);
}
__device__ __forceinline__ unsigned pkrn(float a, float b){
  return (unsigned)f2bf(a) | ((unsigned)f2bf(b) << 16);
}
__device__ __forceinline__ int region(int g){ return (g < 21) ? 0 : ((g < 25) ? 1 : 2); }

// ---------------- K0: bias table in S^T-fragment tile order ----------------
// rpbB[((h*22 + kt)*22 + qt)*256 + lane*4 + reg] = bias for (query=qt*16+(lane&15), key=kt*16+(lane>>4)*4+reg)
// padded keys get -1e30 (exp -> 0); padded queries get 0 (never stored).
__global__ __launch_bounds__(256) void k_rpb(const float* __restrict__ tab, float* __restrict__ rpbB){
  const int bid = blockIdx.x, tid = threadIdx.x;
  const int lane = tid >> 2, reg = tid & 3;
  const int qt = bid % 22, tmp = bid / 22, kt = tmp % 22, hh = tmp / 22;
  const int n = lane & 15, qd = lane >> 4;
  const int i = qt * 16 + n;
  const int j = kt * 16 + qd * 4 + reg;
  float v;
  if (j >= NTOK) v = -1e30f;
  else if (i >= NTOK) v = 0.f;
  else {
    int r1 = i / 49, rm = i - r1 * 49, r2 = rm / 7, r3 = rm - r2 * 7;
    int j1 = j / 49, jm = j - j1 * 49, j2 = jm / 7, j3 = jm - j2 * 7;
    int idx = 13 * ((r1 - j1) + (r2 - j2) + 12) + (r3 - j3) + 6;
    v = tab[idx * 4 + hh];
  }
  rpbB[(size_t)bid * 256 + tid] = v;
}

// ---------------- K1: LN1 + shift-gather + QKV GEMM (per window) ----------------
__global__ __launch_bounds__(256) void k_qkv(
    const float* __restrict__ x, const float* __restrict__ n1w, const float* __restrict__ n1b,
    const float* __restrict__ qw, const float* __restrict__ qb,
    unsigned short* __restrict__ qS, unsigned short* __restrict__ kS, unsigned short* __restrict__ vS)
{
  __shared__ __align__(16) unsigned short xwB[NTOK * 96];
  __shared__ __align__(16) unsigned short wtB[288 * 104];
  const int blk = blockIdx.x, b = blk >> 6, wl = blk & 63;
  const int wx = wl >> 4, wy = (wl >> 2) & 3, wz = wl & 3;
  const int tid = threadIdx.x, lane = tid & 63, wv = tid >> 6;

  for (int i = tid; i < 96 * 288; i += 256){
    int k = i / 288, o = i - k * 288;
    wtB[o * 104 + k] = f2bf(qw[i]);
  }
  const float g1 = n1w[lane], h1 = n1b[lane];
  const float g2 = (lane < 32) ? n1w[64 + lane] : 0.f;
  const float h2 = (lane < 32) ? n1b[64 + lane] : 0.f;
  for (int r = wv; r < NTOK; r += 4){
    int tx = r / 49, rm = r - tx * 49, ty = rm / 7, tz = rm - ty * 7;
    int sx = (wx * 7 + tx + 3) % 28, sy = (wy * 7 + ty + 3) % 28, sz = (wz * 7 + tz + 3) % 28;
    const float* xr = x + ((size_t)b * 21952 + ((sx * 28 + sy) * 28 + sz)) * 96;
    float v1 = xr[lane];
    float v2 = (lane < 32) ? xr[64 + lane] : 0.f;
    float s = v1 + v2, sq = v1 * v1 + v2 * v2;
    #pragma unroll
    for (int off = 32; off; off >>= 1){ s += __shfl_xor(s, off); sq += __shfl_xor(sq, off); }
    float mu = s * (1.f / 96.f);
    float rs = rsqrtf(sq * (1.f / 96.f) - mu * mu + 1e-5f);
    xwB[r * 96 + lane] = f2bf((v1 - mu) * rs * g1 + h1);
    if (lane < 32) xwB[r * 96 + 64 + lane] = f2bf((v2 - mu) * rs * g2 + h2);
  }
  __syncthreads();

  const bool j4 = (lane < 32);
  float bj[5], sc[5];
  unsigned short* op[5];
  #pragma unroll
  for (int j = 0; j < 5; j++){
    int o = lane + 64 * j;
    bool valid = (j < 4) || j4;
    if (!valid) o = 0;
    bj[j] = valid ? qb[o] : 0.f;
    int s3 = o / 96, om = o - s3 * 96, hh = om / 24, d = om - hh * 24;
    unsigned short* base = (s3 == 0) ? qS : ((s3 == 1) ? kS : vS);
    op[j] = base + ((size_t)blk * 4 + hh) * 8232 + d;
    sc[j] = (s3 == 0) ? SCALE : 1.f;
  }
  for (int g = wv; g < 43; g += 4){
    const int r0 = g * 8;
    float acc[8][5];
    #pragma unroll
    for (int rr = 0; rr < 8; rr++)
      #pragma unroll
      for (int j = 0; j < 5; j++) acc[rr][j] = 0.f;
    for (int kc = 0; kc < 12; kc++){
      uint4 xq[8], wq[5];
      #pragma unroll
      for (int rr = 0; rr < 8; rr++){
        int r = r0 + rr; if (r > 342) r = 342;
        xq[rr] = *(const uint4*)(xwB + r * 96 + kc * 8);
      }
      #pragma unroll
      for (int j = 0; j < 5; j++){
        int o = lane + 64 * j; if (j == 4 && !j4) o = 0;
        wq[j] = *(const uint4*)(wtB + o * 104 + kc * 8);
      }
      #pragma unroll
      for (int t = 0; t < 8; t++){
        float wf[5];
        #pragma unroll
        for (int j = 0; j < 5; j++) wf[j] = bfel(wq[j], t);
        #pragma unroll
        for (int rr = 0; rr < 8; rr++){
          float xf = bfel(xq[rr], t);
          #pragma unroll
          for (int j = 0; j < 5; j++) acc[rr][j] = fmaf(xf, wf[j], acc[rr][j]);
        }
      }
    }
    #pragma unroll
    for (int rr = 0; rr < 8; rr++){
      int r = r0 + rr; if (r > 342) continue;
      #pragma unroll
      for (int j = 0; j < 5; j++){
        if (j == 4 && !j4) continue;
        op[j][r * 24] = f2bf((acc[rr][j] + bj[j]) * sc[j]);
      }
    }
  }
}

// ---------------- K2: MFMA attention (per window, head) ----------------
// S^T tiles: A=K-frag (m=key), B=Q-frag (n=query)  -> lane holds (query=lane&15, keys 4*quad+r)
// P -> per-wave LDS round-trip -> B-frag; O^T tiles: A=V^T-frag (m=d), B=P-frag (n=query)
__global__ __launch_bounds__(256, 2) void k_attn(
    const unsigned short* __restrict__ qS, const unsigned short* __restrict__ kS,
    const unsigned short* __restrict__ vS, const float* __restrict__ rpbB,
    unsigned short* __restrict__ aO)
{
  __shared__ __align__(16) unsigned short Ksh[NP * 24];          // [key][d] 16,896 B
  __shared__ __align__(16) unsigned short VTsh[24 * VSTR];       // [d][key] 17,280 B
  __shared__ __align__(16) unsigned short Psh[4 * 16 * PSTR];    // per-wave P buf 5,120 B
  __shared__ __align__(8) unsigned char lab8[NP];

  const int blk = blockIdx.x, w = blk >> 2, h = blk & 3;
  const int tid = threadIdx.x, lane = tid & 63, wv = tid >> 6;
  const int ln = lane & 15, qd = lane >> 4;

  // ---- stage ----
  {
    const unsigned* kg = (const unsigned*)(kS + (size_t)blk * 8232);
    unsigned* kd = (unsigned*)Ksh;
    for (int i = tid; i < 4224; i += 256) kd[i] = (i < 4116) ? kg[i] : 0u;   // zero-pad keys 343..351
    const unsigned* vg = (const unsigned*)(vS + (size_t)blk * 8232);
    for (int i = tid; i < 4116; i += 256){
      unsigned v = vg[i];
      int e0 = 2 * i, key = e0 / 24, d = e0 - key * 24;   // d even -> pair stays in-row
      VTsh[d * VSTR + key] = (unsigned short)(v & 0xffffu);
      VTsh[(d + 1) * VSTR + key] = (unsigned short)(v >> 16);
    }
    for (int i = tid; i < 24 * 13; i += 256){              // zero-pad keys 343..355
      int d = i / 13, kk = 343 + (i - d * 13);
      VTsh[d * VSTR + kk] = 0;
    }
    const int wl = w & 63, wx = wl >> 4, wy = (wl >> 2) & 3, wz = wl & 3;
    for (int n = tid; n < NP; n += 256){
      int tx = n / 49, nm = n - tx * 49, ty = nm / 7, tz = nm - ty * 7;
      lab8[n] = (n < NTOK) ? (unsigned char)(region(wx*7+tx)*9 + region(wy*7+ty)*3 + region(wz*7+tz)) : (unsigned char)0;
    }
  }
  __syncthreads();

  // ---- per-wave query tiles: qt = wv + 4t ----
  bf16x8 qf[6];
  int labQ[6], qts[6];
  #pragma unroll
  for (int t = 0; t < 6; t++){
    int qtr = wv + 4 * t;
    bool val = qtr < 22;
    qts[t] = val ? qtr : -1;
    int qt = val ? qtr : 0;
    int query = qt * 16 + ln;
    uint4 qv = *(const uint4*)(qS + (size_t)blk * 8232 + (size_t)query * 24 + qd * 8);
    if (qd == 3){ qv.x = 0; qv.y = 0; qv.z = 0; qv.w = 0; }   // zero k=24..31 (pad)
    qf[t] = __builtin_bit_cast(bf16x8, qv);
    labQ[t] = lab8[qt * 16 + ln];
  }

  f32x4 accO[6][2];
  float ssum[6];
  #pragma unroll
  for (int t = 0; t < 6; t++){
    ssum[t] = 0.f;
    #pragma unroll
    for (int d2 = 0; d2 < 2; d2++){ accO[t][d2][0]=0.f; accO[t][d2][1]=0.f; accO[t][d2][2]=0.f; accO[t][d2][3]=0.f; }
  }
  const float* biasBase = rpbB + (size_t)h * (22 * 22 * 256);
  unsigned short* pb = Psh + wv * 16 * PSTR + ln * PSTR;      // this wave+lane's P row
  const unsigned short* pr = Psh + wv * 16 * PSTR + ln * PSTR + qd * 8;  // B-frag read addr
  const int vt1row = 16 + (ln & 7);                            // dtile1 row (lanes ln>=8: junk, unstored)
  const f32x4 zf = {0.f, 0.f, 0.f, 0.f};

  for (int kp = 0; kp < 11; kp++){
    uint4 kv0 = *(const uint4*)(Ksh + (kp * 32 + ln) * 24 + qd * 8);
    uint4 kv1 = *(const uint4*)(Ksh + (kp * 32 + 16 + ln) * 24 + qd * 8);
    bf16x8 kf0 = __builtin_bit_cast(bf16x8, kv0);
    bf16x8 kf1 = __builtin_bit_cast(bf16x8, kv1);
    bf16x8 vf0 = *(const bf16x8*)(VTsh + ln * VSTR + kp * 32 + qd * 8);
    bf16x8 vf1 = *(const bf16x8*)(VTsh + vt1row * VSTR + kp * 32 + qd * 8);
    const unsigned* l32 = (const unsigned*)lab8;
    unsigned la = l32[kp * 8 + qd];        // labels keys kp*32+4qd..+3
    unsigned lb = l32[kp * 8 + 4 + qd];    // labels keys kp*32+16+4qd..+3
    int kl0[4], kl1[4];
    #pragma unroll
    for (int r = 0; r < 4; r++){ kl0[r] = (la >> (8 * r)) & 255; kl1[r] = (lb >> (8 * r)) & 255; }

    #pragma unroll
    for (int t = 0; t < 6; t++){
      if (qts[t] < 0) continue;       // wave-uniform
      const int qt = qts[t];
      f32x4 s0 = __builtin_amdgcn_mfma_f32_16x16x32_bf16(kf0, qf[t], zf, 0, 0, 0);
      f32x4 s1 = __builtin_amdgcn_mfma_f32_16x16x32_bf16(kf1, qf[t], zf, 0, 0, 0);
      const float* bp = biasBase + (((size_t)(2 * kp) * 22 + qt) * 64 + lane) * 4;
      float4 b0 = *(const float4*)bp;
      float4 b1 = *(const float4*)(bp + 22 * 256);
      const int lq = labQ[t];
      float e0[4], e1[4];
      #pragma unroll
      for (int r = 0; r < 4; r++){
        float ev = __expf(s0[r] + (&b0.x)[r]);
        e0[r] = (kl0[r] == lq) ? ev : 0.f;
      }
      #pragma unroll
      for (int r = 0; r < 4; r++){
        float ev = __expf(s1[r] + (&b1.x)[r]);
        e1[r] = (kl1[r] == lq) ? ev : 0.f;
      }
      ssum[t] += ((e0[0] + e0[1]) + (e0[2] + e0[3])) + ((e1[0] + e1[1]) + (e1[2] + e1[3]));
      uint2 w0; w0.x = pk2(e0[0], e0[1]); w0.y = pk2(e0[2], e0[3]);
      uint2 w1; w1.x = pk2(e1[0], e1[1]); w1.y = pk2(e1[2], e1[3]);
      *(uint2*)(pb + 4 * qd)      = w0;   // kt0 keys 4qd..4qd+3
      *(uint2*)(pb + 16 + 4 * qd) = w1;   // kt1 keys 16+4qd..+3
      bf16x8 pf = *(const bf16x8*)pr;     // B-frag: (query=ln, keys qd*8..qd*8+7) — same wave, no barrier
      accO[t][0] = __builtin_amdgcn_mfma_f32_16x16x32_bf16(vf0, pf, accO[t][0], 0, 0, 0);
      accO[t][1] = __builtin_amdgcn_mfma_f32_16x16x32_bf16(vf1, pf, accO[t][1], 0, 0, 0);
    }
  }

  // ---- epilogue: cross-quad row-sum, normalize, store bf16 ----
  #pragma unroll
  for (int t = 0; t < 6; t++){
    if (qts[t] < 0) continue;
    float s = ssum[t];
    s += __shfl_xor(s, 16);
    s += __shfl_xor(s, 32);
    float inv = 1.f / s;
    int query = qts[t] * 16 + ln;
    if (query < NTOK){
      unsigned short* dst = aO + (size_t)w * 32928 + (size_t)query * 96 + h * 24;
      uint2 o0;
      o0.x = pkrn(accO[t][0][0] * inv, accO[t][0][1] * inv);
      o0.y = pkrn(accO[t][0][2] * inv, accO[t][0][3] * inv);
      *(uint2*)(dst + 4 * qd) = o0;                  // d = 4qd..4qd+3
      if (qd < 2){
        uint2 o1;
        o1.x = pkrn(accO[t][1][0] * inv, accO[t][1][1] * inv);
        o1.y = pkrn(accO[t][1][2] * inv, accO[t][1][3] * inv);
        *(uint2*)(dst + 16 + 4 * qd) = o1;           // d = 16+4qd..+3 (<24)
      }
    }
  }
}

// ---------------- K3: proj + window-reverse + un-shift + residual -> d_out ----------------
__global__ __launch_bounds__(256) void k_proj(
    const unsigned short* __restrict__ aO, const float* __restrict__ pw, const float* __restrict__ pb,
    const float* __restrict__ x, float* __restrict__ out)
{
  __shared__ __align__(16) unsigned short aB[NTOK * 96];
  __shared__ __align__(16) unsigned short ptB[96 * 104];
  const int blk = blockIdx.x, b = blk >> 6, wl = blk & 63;
  const int wx = wl >> 4, wy = (wl >> 2) & 3, wz = wl & 3;
  const int tid = threadIdx.x, lane = tid & 63, wv = tid >> 6;
  {
    const unsigned* ag = (const unsigned*)(aO + (size_t)blk * 32928);
    unsigned* ad = (unsigned*)aB;
    for (int i = tid; i < 16464; i += 256) ad[i] = ag[i];
  }
  for (int i = tid; i < 96 * 96; i += 256){
    int k = i / 96, o = i - k * 96;
    ptB[o * 104 + k] = f2bf(pw[i]);
  }
  __syncthreads();
  const bool j1v = (lane < 32);
  const int o0 = lane, o1 = 64 + (lane & 31);
  const float pb0 = pb[o0], pb1 = pb[o1];
  for (int g = wv; g < 43; g += 4){
    const int r0 = g * 8;
    float acc[8][2];
    #pragma unroll
    for (int rr = 0; rr < 8; rr++){ acc[rr][0] = 0.f; acc[rr][1] = 0.f; }
    for (int kc = 0; kc < 12; kc++){
      uint4 xq[8];
      #pragma unroll
      for (int rr = 0; rr < 8; rr++){
        int r = r0 + rr; if (r > 342) r = 342;
        xq[rr] = *(const uint4*)(aB + r * 96 + kc * 8);
      }
      uint4 w0 = *(const uint4*)(ptB + o0 * 104 + kc * 8);
      uint4 w1 = *(const uint4*)(ptB + o1 * 104 + kc * 8);
      #pragma unroll
      for (int t = 0; t < 8; t++){
        float f0 = bfel(w0, t), f1 = bfel(w1, t);
        #pragma unroll
        for (int rr = 0; rr < 8; rr++){
          float xf = bfel(xq[rr], t);
          acc[rr][0] = fmaf(xf, f0, acc[rr][0]);
          acc[rr][1] = fmaf(xf, f1, acc[rr][1]);
        }
      }
    }
    #pragma unroll
    for (int rr = 0; rr < 8; rr++){
      int r = r0 + rr; if (r > 342) continue;
      int tx = r / 49, rm = r - tx * 49, ty = rm / 7, tz = rm - ty * 7;
      int sx = (wx * 7 + tx + 3) % 28, sy = (wy * 7 + ty + 3) % 28, sz = (wz * 7 + tz + 3) % 28;
      size_t oi = ((size_t)b * 21952 + ((sx * 28 + sy) * 28 + sz)) * 96;
      out[oi + o0] = acc[rr][0] + pb0 + x[oi + o0];
      if (j1v) out[oi + o1] = acc[rr][1] + pb1 + x[oi + o1];
    }
  }
}

// ---------------- K-prep: fc1/fc2 weights -> bf16 MFMA A-fragment layout ----------------
__global__ __launch_bounds__(256) void k_wprep(
    const float* __restrict__ w1g, const float* __restrict__ w2g,
    unsigned short* __restrict__ w1F, unsigned short* __restrict__ w2F)
{
  int p = blockIdx.x * 256 + threadIdx.x;
  if (p < 36864){
    int e = p & 7, m = (p >> 3) & 15, cell = p >> 7;
    int mt = cell / 12, q = cell - mt * 12;
    w1F[p] = f2bf(w1g[(q * 8 + e) * 384 + mt * 16 + m]);
  } else if (p < 73728){
    int p2 = p - 36864;
    int e = p2 & 7, m = (p2 >> 3) & 15, cell = p2 >> 7;
    int omt = cell / 48, q = cell - omt * 48;
    w2F[p2] = f2bf(w2g[(q * 8 + e) * 96 + omt * 16 + m]);
  }
}

// ---------------- K4: MFMA MLP: LN2 + fc1 + GeLU + fc2 + residual (32 rows/block) ----------------
__global__ __launch_bounds__(256, 4) void k_mlp(
    float* __restrict__ io, const float* __restrict__ n2w, const float* __restrict__ n2b,
    const unsigned short* __restrict__ w1F, const float* __restrict__ b1g,
    const unsigned short* __restrict__ w2F, const float* __restrict__ b2g)
{
  __shared__ __align__(16) unsigned short xnF[2 * 12 * 16 * 8];
  __shared__ __align__(16) unsigned short hF[2 * 48 * 16 * 8];
  const int tid = threadIdx.x, lane = tid & 63, wv = tid >> 6;
  const size_t row0 = (size_t)blockIdx.x * 32;

  const float g1 = n2w[lane], c1 = n2b[lane];
  const float g2 = (lane < 32) ? n2w[64 + lane] : 0.f;
  const float c2 = (lane < 32) ? n2b[64 + lane] : 0.f;
  for (int r = wv; r < 32; r += 4){
    const float* xr = io + (row0 + r) * 96;
    float v1 = xr[lane], v2 = (lane < 32) ? xr[64 + lane] : 0.f;
    float s = v1 + v2, sq = v1 * v1 + v2 * v2;
    #pragma unroll
    for (int off = 32; off; off >>= 1){ s += __shfl_xor(s, off); sq += __shfl_xor(sq, off); }
    float mu = s * (1.f / 96.f);
    float rs = rsqrtf(sq * (1.f / 96.f) - mu * mu + 1e-5f);
    int nt = r >> 4, n = r & 15;
    int c = lane;
    xnF[((nt * 12 + (c >> 3)) * 16 + n) * 8 + (c & 7)] = f2bf((v1 - mu) * rs * g1 + c1);
    if (lane < 32){
      int cc = 64 + lane;
      xnF[((nt * 12 + (cc >> 3)) * 16 + n) * 8 + (cc & 7)] = f2bf((v2 - mu) * rs * g2 + c2);
    }
  }
  __syncthreads();

  const int h = lane & 15, q = lane >> 4;
  const int nt = wv & 1, mh = wv >> 1;

  f32x4 acc[12];
  #pragma unroll
  for (int mt = 0; mt < 12; mt++){
    int o0 = (mh * 12 + mt) * 16 + 4 * q;
    float4 bv = *(const float4*)(b1g + o0);
    acc[mt][0] = bv.x; acc[mt][1] = bv.y; acc[mt][2] = bv.z; acc[mt][3] = bv.w;
  }
  for (int ks = 0; ks < 3; ks++){
    bf16x8 bfr = *(const bf16x8*)(xnF + ((nt * 12 + ks * 4 + q) * 16 + h) * 8);
    #pragma unroll
    for (int mt = 0; mt < 12; mt++){
      bf16x8 afr = *(const bf16x8*)(w1F + (((mh * 12 + mt) * 12 + ks * 4 + q) * 16 + h) * 8);
      acc[mt] = __builtin_amdgcn_mfma_f32_16x16x32_bf16(afr, bfr, acc[mt], 0, 0, 0);
    }
  }
  #pragma unroll
  for (int mt = 0; mt < 12; mt++){
    int o0 = (mh * 12 + mt) * 16 + 4 * q;
    unsigned short pk[4];
    #pragma unroll
    for (int rg = 0; rg < 4; rg++){
      float v = acc[mt][rg];
      pk[rg] = f2bf(0.5f * v * (1.f + erff(v * 0.70710678118654752f)));
    }
    unsigned short* d = hF + ((nt * 48 + (o0 >> 3)) * 16 + h) * 8 + (o0 & 7);
    uint2 pkv; pkv.x = (unsigned)pk[0] | ((unsigned)pk[1] << 16);
    pkv.y = (unsigned)pk[2] | ((unsigned)pk[3] << 16);
    *(uint2*)d = pkv;
  }
  __syncthreads();

  f32x4 acc2[3];
  #pragma unroll
  for (int mt = 0; mt < 3; mt++){
    int o0 = (mh * 3 + mt) * 16 + 4 * q;
    float4 bv = *(const float4*)(b2g + o0);
    acc2[mt][0] = bv.x; acc2[mt][1] = bv.y; acc2[mt][2] = bv.z; acc2[mt][3] = bv.w;
  }
  for (int ks = 0; ks < 12; ks++){
    bf16x8 bfr = *(const bf16x8*)(hF + ((nt * 48 + ks * 4 + q) * 16 + h) * 8);
    #pragma unroll
    for (int mt = 0; mt < 3; mt++){
      bf16x8 afr = *(const bf16x8*)(w2F + (((mh * 3 + mt) * 48 + ks * 4 + q) * 16 + h) * 8);
      acc2[mt] = __builtin_amdgcn_mfma_f32_16x16x32_bf16(afr, bfr, acc2[mt], 0, 0, 0);
    }
  }
  float* orow = io + (row0 + nt * 16 + h) * 96;
  #pragma unroll
  for (int mt = 0; mt < 3; mt++){
    int o0 = (mh * 3 + mt) * 16 + 4 * q;
    float4 cur = *(const float4*)(orow + o0);
    cur.x += acc2[mt][0]; cur.y += acc2[mt][1]; cur.z += acc2[mt][2]; cur.w += acc2[mt][3];
    *(float4*)(orow + o0) = cur;
  }
}

extern "C" void kernel_launch(void* const* d_in, const int* in_sizes, int n_in,
                              void* d_out, int out_size, void* d_ws, size_t ws_size,
                              hipStream_t stream)
{
  const float* x      = (const float*)d_in[0];
  const float* n1w    = (const float*)d_in[1];
  const float* n1b    = (const float*)d_in[2];
  const float* qkvw   = (const float*)d_in[3];
  const float* qkvb   = (const float*)d_in[4];
  const float* rpbtab = (const float*)d_in[5];
  const float* projw  = (const float*)d_in[6];
  const float* projb  = (const float*)d_in[7];
  const float* n2w    = (const float*)d_in[8];
  const float* n2b    = (const float*)d_in[9];
  const float* fc1w   = (const float*)d_in[10];
  const float* fc1b   = (const float*)d_in[11];
  const float* fc2w   = (const float*)d_in[12];
  const float* fc2b   = (const float*)d_in[13];
  float* out = (float*)d_out;

  unsigned short* qS = (unsigned short*)d_ws;
  unsigned short* kS = qS + 8429568;
  unsigned short* vS = kS + 8429568;
  unsigned short* aO = vS + 8429568;
  float* rpbB = (float*)(aO + 8429568);     // 495,616 floats (~2 MB), tile-fragment order
  unsigned short* w1F = qS;                  // alias: only live after k_attn consumed qS
  unsigned short* w2F = qS + 36864;

  k_rpb  <<<dim3(1936), dim3(256), 0, stream>>>(rpbtab, rpbB);
  k_qkv  <<<dim3(256),  dim3(256), 0, stream>>>(x, n1w, n1b, qkvw, qkvb, qS, kS, vS);
  k_attn <<<dim3(1024), dim3(256), 0, stream>>>(qS, kS, vS, rpbB, aO);
  k_wprep<<<dim3(288),  dim3(256), 0, stream>>>(fc1w, fc2w, w1F, w2F);
  k_proj <<<dim3(256),  dim3(256), 0, stream>>>(aO, projw, projb, x, out);
  k_mlp  <<<dim3(2744), dim3(256), 0, stream>>>(out, n2w, n2b, w1F, fc1b, w2F, fc2b);
}

// Round 4
// 318.947 us; speedup vs baseline: 3.6372x; 1.6318x over previous
//
#include <hip/hip_runtime.h>

#define NTOK 343
#define NP   352
#define SCALE 0.2041241452319315f
#define VSTR 360   // VT LDS row stride (halves)
#define PSTR 40    // P buf row stride (halves)

typedef __attribute__((ext_vector_type(8))) short bf16x8;
typedef __attribute__((ext_vector_type(4))) float f32x4;

__device__ __forceinline__ unsigned short f2bf(float f){
  unsigned u = __builtin_bit_cast(unsigned, f);
  u += 0x7fffu + ((u >> 16) & 1u);
  return (unsigned short)(u >> 16);
}
__device__ __forceinline__ float bfel(const uint4& q, int t){
  unsigned u = (&q.x)[t >> 1];
  u = (t & 1) ? (u & 0xffff0000u) : (u << 16);
  return __builtin_bit_cast(float, u);
}
__device__ __forceinline__ unsigned pk2(float a, float b){
  unsigned ua = __builtin_bit_cast(unsigned, a) + 0x8000u;
  unsigned ub = __builtin_bit_cast(unsigned, b) + 0x8000u;
  return __builtin_amdgcn_perm(ub, ua, 0x07060302u);
}
__device__ __forceinline__ unsigned pkrn(float a, float b){
  return (unsigned)f2bf(a) | ((unsigned)f2bf(b) << 16);
}
__device__ __forceinline__ int region(int g){ return (g < 21) ? 0 : ((g < 25) ? 1 : 2); }

// ---------------- K0: bias table in S^T-fragment tile order ----------------
__global__ __launch_bounds__(256) void k_rpb(const float* __restrict__ tab, float* __restrict__ rpbB){
  const int bid = blockIdx.x, tid = threadIdx.x;
  const int lane = tid >> 2, reg = tid & 3;
  const int qt = bid % 22, tmp = bid / 22, kt = tmp % 22, hh = tmp / 22;
  const int n = lane & 15, qd = lane >> 4;
  const int i = qt * 16 + n;
  const int j = kt * 16 + qd * 4 + reg;
  float v;
  if (j >= NTOK) v = -1e30f;
  else if (i >= NTOK) v = 0.f;
  else {
    int r1 = i / 49, rm = i - r1 * 49, r2 = rm / 7, r3 = rm - r2 * 7;
    int j1 = j / 49, jm = j - j1 * 49, j2 = jm / 7, j3 = jm - j2 * 7;
    int idx = 13 * ((r1 - j1) + (r2 - j2) + 12) + (r3 - j3) + 6;
    v = tab[idx * 4 + hh];
  }
  rpbB[(size_t)bid * 256 + tid] = v;
}

// ---------------- K-wprep1: qkv weights -> A-frag layout (runs BEFORE k_qkv; lives in aO region) ----
// wQ[((mt*12+kq)*16+m)*8+e] = qkv_w[k=kq*8+e][o=mt*16+m]   (96 x 288)
__global__ __launch_bounds__(256) void k_wprep1(const float* __restrict__ qw, unsigned short* __restrict__ wQ){
  int p = blockIdx.x * 256 + threadIdx.x;   // 27648 total
  int e = p & 7, m = (p >> 3) & 15, cell = p >> 7;
  int mt = cell / 12, kq = cell - mt * 12;
  wQ[p] = f2bf(qw[(kq * 8 + e) * 288 + mt * 16 + m]);
}

// ---------------- K-wprep2: proj/fc1/fc2 weights -> A-frag layout (runs AFTER k_attn; lives in qS) ----
__global__ __launch_bounds__(256) void k_wprep2(
    const float* __restrict__ pw, const float* __restrict__ w1g, const float* __restrict__ w2g,
    unsigned short* __restrict__ w1F, unsigned short* __restrict__ w2F, unsigned short* __restrict__ wP)
{
  int p = blockIdx.x * 256 + threadIdx.x;   // 82944 total
  if (p < 36864){
    int e = p & 7, m = (p >> 3) & 15, cell = p >> 7;
    int mt = cell / 12, q = cell - mt * 12;
    w1F[p] = f2bf(w1g[(q * 8 + e) * 384 + mt * 16 + m]);
  } else if (p < 73728){
    int p2 = p - 36864;
    int e = p2 & 7, m = (p2 >> 3) & 15, cell = p2 >> 7;
    int omt = cell / 48, q = cell - omt * 48;
    w2F[p2] = f2bf(w2g[(q * 8 + e) * 96 + omt * 16 + m]);
  } else {
    int p3 = p - 73728;
    int e = p3 & 7, m = (p3 >> 3) & 15, cell = p3 >> 7;
    int mt = cell / 12, kq = cell - mt * 12;
    wP[p3] = f2bf(pw[(kq * 8 + e) * 96 + mt * 16 + m]);
  }
}

// ---------------- K1: MFMA LN1 + shift-gather + QKV GEMM (half-window per block) ----------------
__global__ __launch_bounds__(256, 4) void k_qkv(
    const float* __restrict__ x, const float* __restrict__ n1w, const float* __restrict__ n1b,
    const unsigned short* __restrict__ wQ, const float* __restrict__ qb,
    unsigned short* __restrict__ qS, unsigned short* __restrict__ kS, unsigned short* __restrict__ vS)
{
  __shared__ __align__(16) unsigned short xnF[11 * 12 * 16 * 8];   // 33,792 B
  const int blk = blockIdx.x, w = blk >> 1, half = blk & 1;
  const int b = w >> 6, wl = w & 63;
  const int wx = wl >> 4, wy = (wl >> 2) & 3, wz = wl & 3;
  const int tid = threadIdx.x, lane = tid & 63, wv = tid >> 6;

  const float g1 = n1w[lane], h1 = n1b[lane];
  const float g2 = (lane < 32) ? n1w[64 + lane] : 0.f;
  const float h2 = (lane < 32) ? n1b[64 + lane] : 0.f;
  for (int r = wv; r < 176; r += 4){
    int tl = half * 176 + r;
    int tok = (tl < NTOK) ? tl : NTOK - 1;
    int tx = tok / 49, rm = tok - tx * 49, ty = rm / 7, tz = rm - ty * 7;
    int sx = (wx * 7 + tx + 3) % 28, sy = (wy * 7 + ty + 3) % 28, sz = (wz * 7 + tz + 3) % 28;
    const float* xr = x + ((size_t)b * 21952 + ((sx * 28 + sy) * 28 + sz)) * 96;
    float v1 = xr[lane];
    float v2 = (lane < 32) ? xr[64 + lane] : 0.f;
    float s = v1 + v2, sq = v1 * v1 + v2 * v2;
    #pragma unroll
    for (int off = 32; off; off >>= 1){ s += __shfl_xor(s, off); sq += __shfl_xor(sq, off); }
    float mu = s * (1.f / 96.f);
    float rs = rsqrtf(sq * (1.f / 96.f) - mu * mu + 1e-5f);
    int nt = r >> 4, n = r & 15;
    xnF[((nt * 12 + (lane >> 3)) * 16 + n) * 8 + (lane & 7)] = f2bf((v1 - mu) * rs * g1 + h1);
    if (lane < 32){
      int cc = 64 + lane;
      xnF[((nt * 12 + (cc >> 3)) * 16 + n) * 8 + (cc & 7)] = f2bf((v2 - mu) * rs * g2 + h2);
    }
  }
  __syncthreads();

  const int ln = lane & 15, qd = lane >> 4;
  bf16x8 bfr[3][3];
  int nts[3], toks[3];
  #pragma unroll
  for (int t = 0; t < 3; t++){
    int nt = wv + 4 * t;
    nts[t] = (nt < 11) ? nt : -1;
    int ntc = (nt < 11) ? nt : 0;
    toks[t] = half * 176 + ntc * 16 + ln;
    #pragma unroll
    for (int ks = 0; ks < 3; ks++)
      bfr[t][ks] = *(const bf16x8*)(xnF + ((ntc * 12 + ks * 4 + qd) * 16 + ln) * 8);
  }
  for (int mt = 0; mt < 18; mt++){
    bf16x8 afr[3];
    #pragma unroll
    for (int ks = 0; ks < 3; ks++)
      afr[ks] = *(const bf16x8*)(wQ + ((mt * 12 + ks * 4 + qd) * 16 + ln) * 8);
    f32x4 acc[3];
    #pragma unroll
    for (int t = 0; t < 3; t++){ acc[t][0] = 0.f; acc[t][1] = 0.f; acc[t][2] = 0.f; acc[t][3] = 0.f; }
    #pragma unroll
    for (int ks = 0; ks < 3; ks++)
      #pragma unroll
      for (int t = 0; t < 3; t++)
        acc[t] = __builtin_amdgcn_mfma_f32_16x16x32_bf16(afr[ks], bfr[t][ks], acc[t], 0, 0, 0);
    const int o0 = mt * 16 + 4 * qd;
    float4 bv = *(const float4*)(qb + o0);
    const int s3 = o0 / 96, om = o0 - s3 * 96, hh = om / 24, d = om - hh * 24;
    const float sc = (s3 == 0) ? SCALE : 1.f;
    unsigned short* base = (s3 == 0) ? qS : ((s3 == 1) ? kS : vS);
    unsigned short* hb = base + ((size_t)(w * 4 + hh)) * 8232 + d;
    #pragma unroll
    for (int t = 0; t < 3; t++){
      if (nts[t] < 0) continue;
      if (toks[t] < NTOK){
        uint2 st;
        st.x = pkrn((acc[t][0] + bv.x) * sc, (acc[t][1] + bv.y) * sc);
        st.y = pkrn((acc[t][2] + bv.z) * sc, (acc[t][3] + bv.w) * sc);
        *(uint2*)(hb + (size_t)toks[t] * 24) = st;
      }
    }
  }
}

// ---------------- K2: MFMA attention (per window, head) ----------------
__global__ __launch_bounds__(256, 2) void k_attn(
    const unsigned short* __restrict__ qS, const unsigned short* __restrict__ kS,
    const unsigned short* __restrict__ vS, const float* __restrict__ rpbB,
    unsigned short* __restrict__ aO)
{
  __shared__ __align__(16) unsigned short Ksh[NP * 24];
  __shared__ __align__(16) unsigned short VTsh[24 * VSTR];
  __shared__ __align__(16) unsigned short Psh[4 * 16 * PSTR];
  __shared__ __align__(8) unsigned char lab8[NP];

  const int blk = blockIdx.x, w = blk >> 2, h = blk & 3;
  const int tid = threadIdx.x, lane = tid & 63, wv = tid >> 6;
  const int ln = lane & 15, qd = lane >> 4;

  {
    const unsigned* kg = (const unsigned*)(kS + (size_t)blk * 8232);
    unsigned* kd = (unsigned*)Ksh;
    for (int i = tid; i < 4224; i += 256) kd[i] = (i < 4116) ? kg[i] : 0u;
    const unsigned* vg = (const unsigned*)(vS + (size_t)blk * 8232);
    for (int i = tid; i < 4116; i += 256){
      unsigned v = vg[i];
      int e0 = 2 * i, key = e0 / 24, d = e0 - key * 24;
      VTsh[d * VSTR + key] = (unsigned short)(v & 0xffffu);
      VTsh[(d + 1) * VSTR + key] = (unsigned short)(v >> 16);
    }
    for (int i = tid; i < 24 * 13; i += 256){
      int d = i / 13, kk = 343 + (i - d * 13);
      VTsh[d * VSTR + kk] = 0;
    }
    const int wl = w & 63, wx = wl >> 4, wy = (wl >> 2) & 3, wz = wl & 3;
    for (int n = tid; n < NP; n += 256){
      int tx = n / 49, nm = n - tx * 49, ty = nm / 7, tz = nm - ty * 7;
      lab8[n] = (n < NTOK) ? (unsigned char)(region(wx*7+tx)*9 + region(wy*7+ty)*3 + region(wz*7+tz)) : (unsigned char)0;
    }
  }
  __syncthreads();

  bf16x8 qf[6];
  int labQ[6], qts[6];
  #pragma unroll
  for (int t = 0; t < 6; t++){
    int qtr = wv + 4 * t;
    bool val = qtr < 22;
    qts[t] = val ? qtr : -1;
    int qt = val ? qtr : 0;
    int query = qt * 16 + ln;
    uint4 qv = *(const uint4*)(qS + (size_t)blk * 8232 + (size_t)query * 24 + qd * 8);
    if (qd == 3){ qv.x = 0; qv.y = 0; qv.z = 0; qv.w = 0; }
    qf[t] = __builtin_bit_cast(bf16x8, qv);
    labQ[t] = lab8[qt * 16 + ln];
  }

  f32x4 accO[6][2];
  float ssum[6];
  #pragma unroll
  for (int t = 0; t < 6; t++){
    ssum[t] = 0.f;
    #pragma unroll
    for (int d2 = 0; d2 < 2; d2++){ accO[t][d2][0]=0.f; accO[t][d2][1]=0.f; accO[t][d2][2]=0.f; accO[t][d2][3]=0.f; }
  }
  const float* biasBase = rpbB + (size_t)h * (22 * 22 * 256);
  unsigned short* pb = Psh + wv * 16 * PSTR + ln * PSTR;
  const unsigned short* pr = Psh + wv * 16 * PSTR + ln * PSTR + qd * 8;
  const int vt1row = 16 + (ln & 7);
  const f32x4 zf = {0.f, 0.f, 0.f, 0.f};

  for (int kp = 0; kp < 11; kp++){
    uint4 kv0 = *(const uint4*)(Ksh + (kp * 32 + ln) * 24 + qd * 8);
    uint4 kv1 = *(const uint4*)(Ksh + (kp * 32 + 16 + ln) * 24 + qd * 8);
    bf16x8 kf0 = __builtin_bit_cast(bf16x8, kv0);
    bf16x8 kf1 = __builtin_bit_cast(bf16x8, kv1);
    bf16x8 vf0 = *(const bf16x8*)(VTsh + ln * VSTR + kp * 32 + qd * 8);
    bf16x8 vf1 = *(const bf16x8*)(VTsh + vt1row * VSTR + kp * 32 + qd * 8);
    const unsigned* l32 = (const unsigned*)lab8;
    unsigned la = l32[kp * 8 + qd];
    unsigned lb = l32[kp * 8 + 4 + qd];
    int kl0[4], kl1[4];
    #pragma unroll
    for (int r = 0; r < 4; r++){ kl0[r] = (la >> (8 * r)) & 255; kl1[r] = (lb >> (8 * r)) & 255; }

    #pragma unroll
    for (int t = 0; t < 6; t++){
      if (qts[t] < 0) continue;
      const int qt = qts[t];
      f32x4 s0 = __builtin_amdgcn_mfma_f32_16x16x32_bf16(kf0, qf[t], zf, 0, 0, 0);
      f32x4 s1 = __builtin_amdgcn_mfma_f32_16x16x32_bf16(kf1, qf[t], zf, 0, 0, 0);
      const float* bp = biasBase + (((size_t)(2 * kp) * 22 + qt) * 64 + lane) * 4;
      float4 b0 = *(const float4*)bp;
      float4 b1 = *(const float4*)(bp + 22 * 256);
      const int lq = labQ[t];
      float e0[4], e1[4];
      #pragma unroll
      for (int r = 0; r < 4; r++){
        float ev = __expf(s0[r] + (&b0.x)[r]);
        e0[r] = (kl0[r] == lq) ? ev : 0.f;
      }
      #pragma unroll
      for (int r = 0; r < 4; r++){
        float ev = __expf(s1[r] + (&b1.x)[r]);
        e1[r] = (kl1[r] == lq) ? ev : 0.f;
      }
      ssum[t] += ((e0[0] + e0[1]) + (e0[2] + e0[3])) + ((e1[0] + e1[1]) + (e1[2] + e1[3]));
      uint2 w0; w0.x = pk2(e0[0], e0[1]); w0.y = pk2(e0[2], e0[3]);
      uint2 w1; w1.x = pk2(e1[0], e1[1]); w1.y = pk2(e1[2], e1[3]);
      *(uint2*)(pb + 4 * qd)      = w0;
      *(uint2*)(pb + 16 + 4 * qd) = w1;
      bf16x8 pf = *(const bf16x8*)pr;
      accO[t][0] = __builtin_amdgcn_mfma_f32_16x16x32_bf16(vf0, pf, accO[t][0], 0, 0, 0);
      accO[t][1] = __builtin_amdgcn_mfma_f32_16x16x32_bf16(vf1, pf, accO[t][1], 0, 0, 0);
    }
  }

  #pragma unroll
  for (int t = 0; t < 6; t++){
    if (qts[t] < 0) continue;
    float s = ssum[t];
    s += __shfl_xor(s, 16);
    s += __shfl_xor(s, 32);
    float inv = 1.f / s;
    int query = qts[t] * 16 + ln;
    if (query < NTOK){
      unsigned short* dst = aO + (size_t)w * 32928 + (size_t)query * 96 + h * 24;
      uint2 o0;
      o0.x = pkrn(accO[t][0][0] * inv, accO[t][0][1] * inv);
      o0.y = pkrn(accO[t][0][2] * inv, accO[t][0][3] * inv);
      *(uint2*)(dst + 4 * qd) = o0;
      if (qd < 2){
        uint2 o1;
        o1.x = pkrn(accO[t][1][0] * inv, accO[t][1][1] * inv);
        o1.y = pkrn(accO[t][1][2] * inv, accO[t][1][3] * inv);
        *(uint2*)(dst + 16 + 4 * qd) = o1;
      }
    }
  }
}

// ---------------- K3: MFMA proj + window-reverse + un-shift + residual (half-window per block) ----
__global__ __launch_bounds__(256, 4) void k_proj(
    const unsigned short* __restrict__ aO, const unsigned short* __restrict__ wP,
    const float* __restrict__ pb, const float* __restrict__ x, float* __restrict__ out)
{
  __shared__ __align__(16) unsigned short aF[11 * 12 * 16 * 8];   // 33,792 B
  const int blk = blockIdx.x, w = blk >> 1, half = blk & 1;
  const int b = w >> 6, wl = w & 63;
  const int wx = wl >> 4, wy = (wl >> 2) & 3, wz = wl & 3;
  const int tid = threadIdx.x, lane = tid & 63, wv = tid >> 6;

  for (int i = tid; i < 2112; i += 256){
    int r = i / 12, kq = i - r * 12;
    int tl = half * 176 + r;
    uint4 v;
    if (tl < NTOK) v = *(const uint4*)(aO + (size_t)w * 32928 + (size_t)tl * 96 + kq * 8);
    else { v.x = 0u; v.y = 0u; v.z = 0u; v.w = 0u; }
    int nt = r >> 4, n = r & 15;
    *(uint4*)(aF + ((nt * 12 + kq) * 16 + n) * 8) = v;
  }
  __syncthreads();

  const int ln = lane & 15, qd = lane >> 4;
  bf16x8 bfr[3][3];
  int nts[3]; size_t oi[3]; bool tv[3];
  #pragma unroll
  for (int t = 0; t < 3; t++){
    int nt = wv + 4 * t;
    nts[t] = (nt < 11) ? nt : -1;
    int ntc = (nt < 11) ? nt : 0;
    int tok = half * 176 + ntc * 16 + ln;
    tv[t] = (nts[t] >= 0) && (tok < NTOK);
    int tk = (tok < NTOK) ? tok : 0;
    int tx = tk / 49, rm = tk - tx * 49, ty = rm / 7, tz = rm - ty * 7;
    int sx = (wx * 7 + tx + 3) % 28, sy = (wy * 7 + ty + 3) % 28, sz = (wz * 7 + tz + 3) % 28;
    oi[t] = ((size_t)b * 21952 + ((sx * 28 + sy) * 28 + sz)) * 96;
    #pragma unroll
    for (int ks = 0; ks < 3; ks++)
      bfr[t][ks] = *(const bf16x8*)(aF + ((ntc * 12 + ks * 4 + qd) * 16 + ln) * 8);
  }
  for (int mt = 0; mt < 6; mt++){
    bf16x8 afr[3];
    #pragma unroll
    for (int ks = 0; ks < 3; ks++)
      afr[ks] = *(const bf16x8*)(wP + ((mt * 12 + ks * 4 + qd) * 16 + ln) * 8);
    f32x4 acc[3];
    #pragma unroll
    for (int t = 0; t < 3; t++){ acc[t][0] = 0.f; acc[t][1] = 0.f; acc[t][2] = 0.f; acc[t][3] = 0.f; }
    #pragma unroll
    for (int ks = 0; ks < 3; ks++)
      #pragma unroll
      for (int t = 0; t < 3; t++)
        acc[t] = __builtin_amdgcn_mfma_f32_16x16x32_bf16(afr[ks], bfr[t][ks], acc[t], 0, 0, 0);
    const int c0 = mt * 16 + 4 * qd;
    float4 bv = *(const float4*)(pb + c0);
    #pragma unroll
    for (int t = 0; t < 3; t++){
      if (!tv[t]) continue;
      float4 cur = *(const float4*)(x + oi[t] + c0);
      float4 o;
      o.x = acc[t][0] + bv.x + cur.x;
      o.y = acc[t][1] + bv.y + cur.y;
      o.z = acc[t][2] + bv.z + cur.z;
      o.w = acc[t][3] + bv.w + cur.w;
      *(float4*)(out + oi[t] + c0) = o;
    }
  }
}

// ---------------- K4: MFMA MLP: LN2 + fc1 + GeLU + fc2 + residual (32 rows/block) ----------------
__global__ __launch_bounds__(256, 4) void k_mlp(
    float* __restrict__ io, const float* __restrict__ n2w, const float* __restrict__ n2b,
    const unsigned short* __restrict__ w1F, const float* __restrict__ b1g,
    const unsigned short* __restrict__ w2F, const float* __restrict__ b2g)
{
  __shared__ __align__(16) unsigned short xnF[2 * 12 * 16 * 8];
  __shared__ __align__(16) unsigned short hF[2 * 48 * 16 * 8];
  const int tid = threadIdx.x, lane = tid & 63, wv = tid >> 6;
  const size_t row0 = (size_t)blockIdx.x * 32;

  const float g1 = n2w[lane], c1 = n2b[lane];
  const float g2 = (lane < 32) ? n2w[64 + lane] : 0.f;
  const float c2 = (lane < 32) ? n2b[64 + lane] : 0.f;
  for (int r = wv; r < 32; r += 4){
    const float* xr = io + (row0 + r) * 96;
    float v1 = xr[lane], v2 = (lane < 32) ? xr[64 + lane] : 0.f;
    float s = v1 + v2, sq = v1 * v1 + v2 * v2;
    #pragma unroll
    for (int off = 32; off; off >>= 1){ s += __shfl_xor(s, off); sq += __shfl_xor(sq, off); }
    float mu = s * (1.f / 96.f);
    float rs = rsqrtf(sq * (1.f / 96.f) - mu * mu + 1e-5f);
    int nt = r >> 4, n = r & 15;
    xnF[((nt * 12 + (lane >> 3)) * 16 + n) * 8 + (lane & 7)] = f2bf((v1 - mu) * rs * g1 + c1);
    if (lane < 32){
      int cc = 64 + lane;
      xnF[((nt * 12 + (cc >> 3)) * 16 + n) * 8 + (cc & 7)] = f2bf((v2 - mu) * rs * g2 + c2);
    }
  }
  __syncthreads();

  const int h = lane & 15, q = lane >> 4;
  const int nt = wv & 1, mh = wv >> 1;

  f32x4 acc[12];
  #pragma unroll
  for (int mt = 0; mt < 12; mt++){
    int o0 = (mh * 12 + mt) * 16 + 4 * q;
    float4 bv = *(const float4*)(b1g + o0);
    acc[mt][0] = bv.x; acc[mt][1] = bv.y; acc[mt][2] = bv.z; acc[mt][3] = bv.w;
  }
  for (int ks = 0; ks < 3; ks++){
    bf16x8 bfr = *(const bf16x8*)(xnF + ((nt * 12 + ks * 4 + q) * 16 + h) * 8);
    #pragma unroll
    for (int mt = 0; mt < 12; mt++){
      bf16x8 afr = *(const bf16x8*)(w1F + (((mh * 12 + mt) * 12 + ks * 4 + q) * 16 + h) * 8);
      acc[mt] = __builtin_amdgcn_mfma_f32_16x16x32_bf16(afr, bfr, acc[mt], 0, 0, 0);
    }
  }
  #pragma unroll
  for (int mt = 0; mt < 12; mt++){
    int o0 = (mh * 12 + mt) * 16 + 4 * q;
    unsigned short pk[4];
    #pragma unroll
    for (int rg = 0; rg < 4; rg++){
      float v = acc[mt][rg];
      pk[rg] = f2bf(0.5f * v * (1.f + erff(v * 0.70710678118654752f)));
    }
    unsigned short* d = hF + ((nt * 48 + (o0 >> 3)) * 16 + h) * 8 + (o0 & 7);
    uint2 pkv; pkv.x = (unsigned)pk[0] | ((unsigned)pk[1] << 16);
    pkv.y = (unsigned)pk[2] | ((unsigned)pk[3] << 16);
    *(uint2*)d = pkv;
  }
  __syncthreads();

  f32x4 acc2[3];
  #pragma unroll
  for (int mt = 0; mt < 3; mt++){
    int o0 = (mh * 3 + mt) * 16 + 4 * q;
    float4 bv = *(const float4*)(b2g + o0);
    acc2[mt][0] = bv.x; acc2[mt][1] = bv.y; acc2[mt][2] = bv.z; acc2[mt][3] = bv.w;
  }
  for (int ks = 0; ks < 12; ks++){
    bf16x8 bfr = *(const bf16x8*)(hF + ((nt * 48 + ks * 4 + q) * 16 + h) * 8);
    #pragma unroll
    for (int mt = 0; mt < 3; mt++){
      bf16x8 afr = *(const bf16x8*)(w2F + (((mh * 3 + mt) * 48 + ks * 4 + q) * 16 + h) * 8);
      acc2[mt] = __builtin_amdgcn_mfma_f32_16x16x32_bf16(afr, bfr, acc2[mt], 0, 0, 0);
    }
  }
  float* orow = io + (row0 + nt * 16 + h) * 96;
  #pragma unroll
  for (int mt = 0; mt < 3; mt++){
    int o0 = (mh * 3 + mt) * 16 + 4 * q;
    float4 cur = *(const float4*)(orow + o0);
    cur.x += acc2[mt][0]; cur.y += acc2[mt][1]; cur.z += acc2[mt][2]; cur.w += acc2[mt][3];
    *(float4*)(orow + o0) = cur;
  }
}

extern "C" void kernel_launch(void* const* d_in, const int* in_sizes, int n_in,
                              void* d_out, int out_size, void* d_ws, size_t ws_size,
                              hipStream_t stream)
{
  const float* x      = (const float*)d_in[0];
  const float* n1w    = (const float*)d_in[1];
  const float* n1b    = (const float*)d_in[2];
  const float* qkvw   = (const float*)d_in[3];
  const float* qkvb   = (const float*)d_in[4];
  const float* rpbtab = (const float*)d_in[5];
  const float* projw  = (const float*)d_in[6];
  const float* projb  = (const float*)d_in[7];
  const float* n2w    = (const float*)d_in[8];
  const float* n2b    = (const float*)d_in[9];
  const float* fc1w   = (const float*)d_in[10];
  const float* fc1b   = (const float*)d_in[11];
  const float* fc2w   = (const float*)d_in[12];
  const float* fc2b   = (const float*)d_in[13];
  float* out = (float*)d_out;

  unsigned short* qS = (unsigned short*)d_ws;
  unsigned short* kS = qS + 8429568;
  unsigned short* vS = kS + 8429568;
  unsigned short* aO = vS + 8429568;
  float* rpbB = (float*)(aO + 8429568);     // ~2 MB, tile-fragment order
  // aliases (no new workspace): wQ lives in aO (dead until k_attn writes it);
  // w1F/w2F/wP live in qS (dead after k_attn reads it)
  unsigned short* wQ  = aO;
  unsigned short* w1F = qS;
  unsigned short* w2F = qS + 36864;
  unsigned short* wP  = qS + 73728;

  k_rpb   <<<dim3(1936), dim3(256), 0, stream>>>(rpbtab, rpbB);
  k_wprep1<<<dim3(108),  dim3(256), 0, stream>>>(qkvw, wQ);
  k_qkv   <<<dim3(512),  dim3(256), 0, stream>>>(x, n1w, n1b, wQ, qkvb, qS, kS, vS);
  k_attn  <<<dim3(1024), dim3(256), 0, stream>>>(qS, kS, vS, rpbB, aO);
  k_wprep2<<<dim3(324),  dim3(256), 0, stream>>>(projw, fc1w, fc2w, w1F, w2F, wP);
  k_proj  <<<dim3(512),  dim3(256), 0, stream>>>(aO, wP, projb, x, out);
  k_mlp   <<<dim3(2744), dim3(256), 0, stream>>>(out, n2w, n2b, w1F, fc1b, w2F, fc2b);
}

// Round 6
// 285.151 us; speedup vs baseline: 4.0682x; 1.1185x over previous
//
#include <hip/hip_runtime.h>

#define NTOK 343
#define NP   352
#define SCALE 0.2041241452319315f
#define LOG2E 1.44269504088896340736f
#define VSTR 360   // VT LDS row stride (halves)
#define PSTR 40    // P buf row stride (halves)

typedef __attribute__((ext_vector_type(8))) short bf16x8;
typedef __attribute__((ext_vector_type(4))) float f32x4;

__device__ __forceinline__ unsigned short f2bf(float f){
  unsigned u = __builtin_bit_cast(unsigned, f);
  u += 0x7fffu + ((u >> 16) & 1u);
  return (unsigned short)(u >> 16);
}
__device__ __forceinline__ float bflo(unsigned u){ return __builtin_bit_cast(float, u << 16); }
__device__ __forceinline__ float bfhi(unsigned u){ return __builtin_bit_cast(float, u & 0xffff0000u); }
__device__ __forceinline__ unsigned pk2(float a, float b){
  unsigned ua = __builtin_bit_cast(unsigned, a) + 0x8000u;
  unsigned ub = __builtin_bit_cast(unsigned, b) + 0x8000u;
  return __builtin_amdgcn_perm(ub, ua, 0x07060302u);
}
__device__ __forceinline__ unsigned pkrn(float a, float b){
  return (unsigned)f2bf(a) | ((unsigned)f2bf(b) << 16);
}
__device__ __forceinline__ int region(int g){ return (g < 21) ? 0 : ((g < 25) ? 1 : 2); }

// ---------------- K0: bias table, bf16, log2-domain, per-lane uint4 order ----------------
// rpbH[bid*512 + lane*8 + slot], bid=(h*11+kp)*22+qt, slot = kth*4+reg:
//   bias(query=qt*16+(lane&15), key=(2kp+kth)*16+(lane>>4)*4+reg) * log2e
__global__ __launch_bounds__(256) void k_rpb(const float* __restrict__ tab, unsigned short* __restrict__ rpbH){
  const int bid = blockIdx.x;
  const int qt = bid % 22, t2 = bid / 22, kp = t2 % 11, h = t2 / 11;
  for (int e = threadIdx.x; e < 512; e += 256){
    int lane = e >> 3, slot = e & 7;
    int kth = slot >> 2, reg = slot & 3;
    int n = lane & 15, qd = lane >> 4;
    int i = qt * 16 + n;
    int j = (2 * kp + kth) * 16 + qd * 4 + reg;
    float v;
    if (j >= NTOK) v = -1e30f;
    else if (i >= NTOK) v = 0.f;
    else {
      int r1 = i / 49, rm = i - r1 * 49, r2 = rm / 7, r3 = rm - r2 * 7;
      int j1 = j / 49, jm = j - j1 * 49, j2 = jm / 7, j3 = jm - j2 * 7;
      int idx = 13 * ((r1 - j1) + (r2 - j2) + 12) + (r3 - j3) + 6;
      v = tab[idx * 4 + h] * LOG2E;
    }
    rpbH[(size_t)bid * 512 + e] = f2bf(v);
  }
}

// ---------------- K-wprep1: qkv weights -> A-frag layout (lives in aO region) ----------------
__global__ __launch_bounds__(256) void k_wprep1(const float* __restrict__ qw, unsigned short* __restrict__ wQ){
  int p = blockIdx.x * 256 + threadIdx.x;   // 27648 total
  int e = p & 7, m = (p >> 3) & 15, cell = p >> 7;
  int mt = cell / 12, kq = cell - mt * 12;
  wQ[p] = f2bf(qw[(kq * 8 + e) * 288 + mt * 16 + m]);
}

// ---------------- K-wprep2: proj/fc1/fc2 weights -> A-frag layout (lives in qS) ----------------
__global__ __launch_bounds__(256) void k_wprep2(
    const float* __restrict__ pw, const float* __restrict__ w1g, const float* __restrict__ w2g,
    unsigned short* __restrict__ w1F, unsigned short* __restrict__ w2F, unsigned short* __restrict__ wP)
{
  int p = blockIdx.x * 256 + threadIdx.x;   // 82944 total
  if (p < 36864){
    int e = p & 7, m = (p >> 3) & 15, cell = p >> 7;
    int mt = cell / 12, q = cell - mt * 12;
    w1F[p] = f2bf(w1g[(q * 8 + e) * 384 + mt * 16 + m]);
  } else if (p < 73728){
    int p2 = p - 36864;
    int e = p2 & 7, m = (p2 >> 3) & 15, cell = p2 >> 7;
    int omt = cell / 48, q = cell - omt * 48;
    w2F[p2] = f2bf(w2g[(q * 8 + e) * 96 + omt * 16 + m]);
  } else {
    int p3 = p - 73728;
    int e = p3 & 7, m = (p3 >> 3) & 15, cell = p3 >> 7;
    int mt = cell / 12, kq = cell - mt * 12;
    wP[p3] = f2bf(pw[(kq * 8 + e) * 96 + mt * 16 + m]);
  }
}

// ---------------- K1: MFMA LN1 + shift-gather + QKV GEMM (half-window per block) ----------------
// q scaled by SCALE*log2e; v written pre-transposed to vT [w*4+h][d][key] rows stride 344
__global__ __launch_bounds__(256, 4) void k_qkv(
    const float* __restrict__ x, const float* __restrict__ n1w, const float* __restrict__ n1b,
    const unsigned short* __restrict__ wQ, const float* __restrict__ qb,
    unsigned short* __restrict__ qS, unsigned short* __restrict__ kS, unsigned short* __restrict__ vT)
{
  __shared__ __align__(16) unsigned short xnF[11 * 12 * 16 * 8];   // 33,792 B
  const int blk = blockIdx.x, w = blk >> 1, half = blk & 1;
  const int b = w >> 6, wl = w & 63;
  const int wx = wl >> 4, wy = (wl >> 2) & 3, wz = wl & 3;
  const int tid = threadIdx.x, lane = tid & 63, wv = tid >> 6;

  const float g1 = n1w[lane], h1 = n1b[lane];
  const float g2 = (lane < 32) ? n1w[64 + lane] : 0.f;
  const float h2 = (lane < 32) ? n1b[64 + lane] : 0.f;
  for (int r = wv; r < 176; r += 4){
    int tl = half * 176 + r;
    int tok = (tl < NTOK) ? tl : NTOK - 1;
    int tx = tok / 49, rm = tok - tx * 49, ty = rm / 7, tz = rm - ty * 7;
    int sx = (wx * 7 + tx + 3) % 28, sy = (wy * 7 + ty + 3) % 28, sz = (wz * 7 + tz + 3) % 28;
    const float* xr = x + ((size_t)b * 21952 + ((sx * 28 + sy) * 28 + sz)) * 96;
    float v1 = xr[lane];
    float v2 = (lane < 32) ? xr[64 + lane] : 0.f;
    float s = v1 + v2, sq = v1 * v1 + v2 * v2;
    #pragma unroll
    for (int off = 32; off; off >>= 1){ s += __shfl_xor(s, off); sq += __shfl_xor(sq, off); }
    float mu = s * (1.f / 96.f);
    float rs = rsqrtf(sq * (1.f / 96.f) - mu * mu + 1e-5f);
    int nt = r >> 4, n = r & 15;
    xnF[((nt * 12 + (lane >> 3)) * 16 + n) * 8 + (lane & 7)] = f2bf((v1 - mu) * rs * g1 + h1);
    if (lane < 32){
      int cc = 64 + lane;
      xnF[((nt * 12 + (cc >> 3)) * 16 + n) * 8 + (cc & 7)] = f2bf((v2 - mu) * rs * g2 + h2);
    }
  }
  __syncthreads();

  const int ln = lane & 15, qd = lane >> 4;
  bf16x8 bfr[3][3];
  int nts[3], toks[3];
  #pragma unroll
  for (int t = 0; t < 3; t++){
    int nt = wv + 4 * t;
    nts[t] = (nt < 11) ? nt : -1;
    int ntc = (nt < 11) ? nt : 0;
    toks[t] = half * 176 + ntc * 16 + ln;
    #pragma unroll
    for (int ks = 0; ks < 3; ks++)
      bfr[t][ks] = *(const bf16x8*)(xnF + ((ntc * 12 + ks * 4 + qd) * 16 + ln) * 8);
  }
  for (int mt = 0; mt < 18; mt++){
    bf16x8 afr[3];
    #pragma unroll
    for (int ks = 0; ks < 3; ks++)
      afr[ks] = *(const bf16x8*)(wQ + ((mt * 12 + ks * 4 + qd) * 16 + ln) * 8);
    f32x4 acc[3];
    #pragma unroll
    for (int t = 0; t < 3; t++){ acc[t][0] = 0.f; acc[t][1] = 0.f; acc[t][2] = 0.f; acc[t][3] = 0.f; }
    #pragma unroll
    for (int ks = 0; ks < 3; ks++)
      #pragma unroll
      for (int t = 0; t < 3; t++)
        acc[t] = __builtin_amdgcn_mfma_f32_16x16x32_bf16(afr[ks], bfr[t][ks], acc[t], 0, 0, 0);
    const int o0 = mt * 16 + 4 * qd;
    float4 bv = *(const float4*)(qb + o0);
    const int s3 = o0 / 96, om = o0 - s3 * 96, hh = om / 24, dd = om - hh * 24;
    if (s3 < 2){
      const float sc = (s3 == 0) ? (SCALE * LOG2E) : 1.f;
      unsigned short* hb = ((s3 == 0) ? qS : kS) + ((size_t)(w * 4 + hh)) * 8232 + dd;
      #pragma unroll
      for (int t = 0; t < 3; t++){
        if (nts[t] < 0 || toks[t] >= NTOK) continue;
        uint2 st;
        st.x = pkrn((acc[t][0] + bv.x) * sc, (acc[t][1] + bv.y) * sc);
        st.y = pkrn((acc[t][2] + bv.z) * sc, (acc[t][3] + bv.w) * sc);
        *(uint2*)(hb + (size_t)toks[t] * 24) = st;
      }
    } else {
      unsigned short* hb = vT + ((size_t)(w * 4 + hh)) * 8256 + (size_t)dd * 344;
      #pragma unroll
      for (int t = 0; t < 3; t++){
        if (nts[t] < 0 || toks[t] >= NTOK) continue;
        hb[0 * 344 + toks[t]] = f2bf(acc[t][0] + bv.x);
        hb[1 * 344 + toks[t]] = f2bf(acc[t][1] + bv.y);
        hb[2 * 344 + toks[t]] = f2bf(acc[t][2] + bv.z);
        hb[3 * 344 + toks[t]] = f2bf(acc[t][3] + bv.w);
      }
    }
  }
}

// ---------------- K2: MFMA attention (per window, head) ----------------
// S = mfma(K, Q, C=bias) in log2-domain; exp2; row-sum via ones-row in V^T tile1.
__global__ __launch_bounds__(256, 4) void k_attn(
    const unsigned short* __restrict__ qS, const unsigned short* __restrict__ kS,
    const unsigned short* __restrict__ vT, const unsigned short* __restrict__ rpbH,
    unsigned short* __restrict__ aO)
{
  __shared__ __align__(16) unsigned short VTsh[25 * VSTR];   // 18,000 B (row 24 = ones)
  __shared__ __align__(16) unsigned short Psh[4 * 16 * PSTR];
  __shared__ __align__(8) unsigned char lab8[NP];

  const int blk = blockIdx.x, w = blk >> 2, h = blk & 3;
  const int tid = threadIdx.x, lane = tid & 63, wv = tid >> 6;
  const int ln = lane & 15, qd = lane >> 4;

  // ---- stage: coalesced V^T copy + zero pad cols + ones row + labels ----
  {
    const unsigned* vg = (const unsigned*)(vT + (size_t)blk * 8256);
    unsigned* vd = (unsigned*)VTsh;
    for (int i = tid; i < 4128; i += 256){
      int d = i / 172, c = i - d * 172;
      vd[d * 180 + c] = vg[i];
    }
    // zero pad columns 344..359 (dwords 172..179) of rows 0..23  [NaN fix: was uninit LDS]
    for (int i = tid; i < 192; i += 256){
      int d = i >> 3, c = i & 7;
      vd[d * 180 + 172 + c] = 0u;
    }
    for (int i = tid; i < 180; i += 256) vd[24 * 180 + i] = 0x3f803f80u;
    const int wl = w & 63, wx = wl >> 4, wy = (wl >> 2) & 3, wz = wl & 3;
    for (int n = tid; n < NP; n += 256){
      int tx = n / 49, nm = n - tx * 49, ty = nm / 7, tz = nm - ty * 7;
      lab8[n] = (n < NTOK) ? (unsigned char)(region(wx*7+tx)*9 + region(wy*7+ty)*3 + region(wz*7+tz)) : (unsigned char)0;
    }
  }
  __syncthreads();

  // ---- per-wave query tiles: qt = wv + 4t ----
  bf16x8 qf[6];
  int labQ[6], qts[6];
  #pragma unroll
  for (int t = 0; t < 6; t++){
    int qtr = wv + 4 * t;
    bool val = qtr < 22;
    qts[t] = val ? qtr : -1;
    int qt = val ? qtr : 0;
    int query = qt * 16 + ln;
    uint4 qv = *(const uint4*)(qS + (size_t)blk * 8232 + (size_t)query * 24 + qd * 8);
    if (qd == 3){ qv.x = 0; qv.y = 0; qv.z = 0; qv.w = 0; }
    qf[t] = __builtin_bit_cast(bf16x8, qv);
    labQ[t] = lab8[qt * 16 + ln];
  }

  f32x4 accO[6][2];
  #pragma unroll
  for (int t = 0; t < 6; t++)
    #pragma unroll
    for (int d2 = 0; d2 < 2; d2++){ accO[t][d2][0]=0.f; accO[t][d2][1]=0.f; accO[t][d2][2]=0.f; accO[t][d2][3]=0.f; }

  const unsigned short* biasBase = rpbH + (size_t)h * (11 * 22 * 512);
  unsigned short* pb = Psh + wv * 16 * PSTR + ln * PSTR;
  const unsigned short* pr = Psh + wv * 16 * PSTR + ln * PSTR + qd * 8;
  const int vrow1 = (ln < 8) ? (16 + ln) : 24;      // ones row -> accO[1] rows 8..15 = sum(P)
  const size_t kbase = (size_t)blk * 8232;

  for (int kp = 0; kp < 11; kp++){
    uint4 kv0 = *(const uint4*)(kS + kbase + (size_t)(kp * 32 + ln) * 24 + qd * 8);
    uint4 kv1 = *(const uint4*)(kS + kbase + (size_t)(kp * 32 + 16 + ln) * 24 + qd * 8);
    bf16x8 kf0 = __builtin_bit_cast(bf16x8, kv0);
    bf16x8 kf1 = __builtin_bit_cast(bf16x8, kv1);
    bf16x8 vf0 = *(const bf16x8*)(VTsh + ln * VSTR + kp * 32 + qd * 8);
    bf16x8 vf1 = *(const bf16x8*)(VTsh + vrow1 * VSTR + kp * 32 + qd * 8);
    const unsigned* l32 = (const unsigned*)lab8;
    unsigned la = l32[kp * 8 + qd];
    unsigned lb = l32[kp * 8 + 4 + qd];
    int kl0[4], kl1[4];
    #pragma unroll
    for (int r = 0; r < 4; r++){ kl0[r] = (la >> (8 * r)) & 255; kl1[r] = (lb >> (8 * r)) & 255; }

    #pragma unroll
    for (int t = 0; t < 6; t++){
      if (qts[t] < 0) continue;
      const int qt = qts[t];
      uint4 bv = *(const uint4*)(biasBase + (((size_t)kp * 22 + qt) * 64 + lane) * 8);
      f32x4 C0, C1;
      C0[0] = bflo(bv.x); C0[1] = bfhi(bv.x); C0[2] = bflo(bv.y); C0[3] = bfhi(bv.y);
      C1[0] = bflo(bv.z); C1[1] = bfhi(bv.z); C1[2] = bflo(bv.w); C1[3] = bfhi(bv.w);
      f32x4 s0 = __builtin_amdgcn_mfma_f32_16x16x32_bf16(kf0, qf[t], C0, 0, 0, 0);
      f32x4 s1 = __builtin_amdgcn_mfma_f32_16x16x32_bf16(kf1, qf[t], C1, 0, 0, 0);
      const int lq = labQ[t];
      float e0[4], e1[4];
      #pragma unroll
      for (int r = 0; r < 4; r++){
        float ev = __builtin_amdgcn_exp2f(s0[r]);
        e0[r] = (kl0[r] == lq) ? ev : 0.f;
      }
      #pragma unroll
      for (int r = 0; r < 4; r++){
        float ev = __builtin_amdgcn_exp2f(s1[r]);
        e1[r] = (kl1[r] == lq) ? ev : 0.f;
      }
      uint2 w0; w0.x = pk2(e0[0], e0[1]); w0.y = pk2(e0[2], e0[3]);
      uint2 w1; w1.x = pk2(e1[0], e1[1]); w1.y = pk2(e1[2], e1[3]);
      *(uint2*)(pb + 4 * qd)      = w0;
      *(uint2*)(pb + 16 + 4 * qd) = w1;
      bf16x8 pf = *(const bf16x8*)pr;     // same-wave LDS round-trip
      accO[t][0] = __builtin_amdgcn_mfma_f32_16x16x32_bf16(vf0, pf, accO[t][0], 0, 0, 0);
      accO[t][1] = __builtin_amdgcn_mfma_f32_16x16x32_bf16(vf1, pf, accO[t][1], 0, 0, 0);
    }
  }

  // ---- epilogue: ssum = accO[1] row 8 (lanes 32..47), fetch via shfl ----
  #pragma unroll
  for (int t = 0; t < 6; t++){
    if (qts[t] < 0) continue;
    float ss = __shfl(accO[t][1][0], 32 + ln);
    float inv = 1.f / ss;
    int query = qts[t] * 16 + ln;
    if (query < NTOK){
      unsigned short* dst = aO + (size_t)w * 32928 + (size_t)query * 96 + h * 24;
      uint2 o0;
      o0.x = pkrn(accO[t][0][0] * inv, accO[t][0][1] * inv);
      o0.y = pkrn(accO[t][0][2] * inv, accO[t][0][3] * inv);
      *(uint2*)(dst + 4 * qd) = o0;
      if (qd < 2){
        uint2 o1;
        o1.x = pkrn(accO[t][1][0] * inv, accO[t][1][1] * inv);
        o1.y = pkrn(accO[t][1][2] * inv, accO[t][1][3] * inv);
        *(uint2*)(dst + 16 + 4 * qd) = o1;
      }
    }
  }
}

// ---------------- K3: MFMA proj + window-reverse + un-shift + residual ----------------
__global__ __launch_bounds__(256, 4) void k_proj(
    const unsigned short* __restrict__ aO, const unsigned short* __restrict__ wP,
    const float* __restrict__ pb, const float* __restrict__ x, float* __restrict__ out)
{
  __shared__ __align__(16) unsigned short aF[11 * 12 * 16 * 8];   // 33,792 B
  const int blk = blockIdx.x, w = blk >> 1, half = blk & 1;
  const int b = w >> 6, wl = w & 63;
  const int wx = wl >> 4, wy = (wl >> 2) & 3, wz = wl & 3;
  const int tid = threadIdx.x, lane = tid & 63, wv = tid >> 6;

  for (int i = tid; i < 2112; i += 256){
    int r = i / 12, kq = i - r * 12;
    int tl = half * 176 + r;
    uint4 v;
    if (tl < NTOK) v = *(const uint4*)(aO + (size_t)w * 32928 + (size_t)tl * 96 + kq * 8);
    else { v.x = 0u; v.y = 0u; v.z = 0u; v.w = 0u; }
    int nt = r >> 4, n = r & 15;
    *(uint4*)(aF + ((nt * 12 + kq) * 16 + n) * 8) = v;
  }
  __syncthreads();

  const int ln = lane & 15, qd = lane >> 4;
  bf16x8 bfr[3][3];
  int nts[3]; size_t oi[3]; bool tv[3];
  #pragma unroll
  for (int t = 0; t < 3; t++){
    int nt = wv + 4 * t;
    nts[t] = (nt < 11) ? nt : -1;
    int ntc = (nt < 11) ? nt : 0;
    int tok = half * 176 + ntc * 16 + ln;
    tv[t] = (nts[t] >= 0) && (tok < NTOK);
    int tk = (tok < NTOK) ? tok : 0;
    int tx = tk / 49, rm = tk - tx * 49, ty = rm / 7, tz = rm - ty * 7;
    int sx = (wx * 7 + tx + 3) % 28, sy = (wy * 7 + ty + 3) % 28, sz = (wz * 7 + tz + 3) % 28;
    oi[t] = ((size_t)b * 21952 + ((sx * 28 + sy) * 28 + sz)) * 96;
    #pragma unroll
    for (int ks = 0; ks < 3; ks++)
      bfr[t][ks] = *(const bf16x8*)(aF + ((ntc * 12 + ks * 4 + qd) * 16 + ln) * 8);
  }
  for (int mt = 0; mt < 6; mt++){
    bf16x8 afr[3];
    #pragma unroll
    for (int ks = 0; ks < 3; ks++)
      afr[ks] = *(const bf16x8*)(wP + ((mt * 12 + ks * 4 + qd) * 16 + ln) * 8);
    f32x4 acc[3];
    #pragma unroll
    for (int t = 0; t < 3; t++){ acc[t][0] = 0.f; acc[t][1] = 0.f; acc[t][2] = 0.f; acc[t][3] = 0.f; }
    #pragma unroll
    for (int ks = 0; ks < 3; ks++)
      #pragma unroll
      for (int t = 0; t < 3; t++)
        acc[t] = __builtin_amdgcn_mfma_f32_16x16x32_bf16(afr[ks], bfr[t][ks], acc[t], 0, 0, 0);
    const int c0 = mt * 16 + 4 * qd;
    float4 bv = *(const float4*)(pb + c0);
    #pragma unroll
    for (int t = 0; t < 3; t++){
      if (!tv[t]) continue;
      float4 cur = *(const float4*)(x + oi[t] + c0);
      float4 o;
      o.x = acc[t][0] + bv.x + cur.x;
      o.y = acc[t][1] + bv.y + cur.y;
      o.z = acc[t][2] + bv.z + cur.z;
      o.w = acc[t][3] + bv.w + cur.w;
      *(float4*)(out + oi[t] + c0) = o;
    }
  }
}

// ---------------- K4: MFMA MLP: LN2 + fc1 + GeLU + fc2 + residual (32 rows/block) ----------------
__global__ __launch_bounds__(256, 4) void k_mlp(
    float* __restrict__ io, const float* __restrict__ n2w, const float* __restrict__ n2b,
    const unsigned short* __restrict__ w1F, const float* __restrict__ b1g,
    const unsigned short* __restrict__ w2F, const float* __restrict__ b2g)
{
  __shared__ __align__(16) unsigned short xnF[2 * 12 * 16 * 8];
  __shared__ __align__(16) unsigned short hF[2 * 48 * 16 * 8];
  const int tid = threadIdx.x, lane = tid & 63, wv = tid >> 6;
  const size_t row0 = (size_t)blockIdx.x * 32;

  const float g1 = n2w[lane], c1 = n2b[lane];
  const float g2 = (lane < 32) ? n2w[64 + lane] : 0.f;
  const float c2 = (lane < 32) ? n2b[64 + lane] : 0.f;
  for (int r = wv; r < 32; r += 4){
    const float* xr = io + (row0 + r) * 96;
    float v1 = xr[lane], v2 = (lane < 32) ? xr[64 + lane] : 0.f;
    float s = v1 + v2, sq = v1 * v1 + v2 * v2;
    #pragma unroll
    for (int off = 32; off; off >>= 1){ s += __shfl_xor(s, off); sq += __shfl_xor(sq, off); }
    float mu = s * (1.f / 96.f);
    float rs = rsqrtf(sq * (1.f / 96.f) - mu * mu + 1e-5f);
    int nt = r >> 4, n = r & 15;
    xnF[((nt * 12 + (lane >> 3)) * 16 + n) * 8 + (lane & 7)] = f2bf((v1 - mu) * rs * g1 + c1);
    if (lane < 32){
      int cc = 64 + lane;
      xnF[((nt * 12 + (cc >> 3)) * 16 + n) * 8 + (cc & 7)] = f2bf((v2 - mu) * rs * g2 + c2);
    }
  }
  __syncthreads();

  const int h = lane & 15, q = lane >> 4;
  const int nt = wv & 1, mh = wv >> 1;

  f32x4 acc[12];
  #pragma unroll
  for (int mt = 0; mt < 12; mt++){
    int o0 = (mh * 12 + mt) * 16 + 4 * q;
    float4 bv = *(const float4*)(b1g + o0);
    acc[mt][0] = bv.x; acc[mt][1] = bv.y; acc[mt][2] = bv.z; acc[mt][3] = bv.w;
  }
  for (int ks = 0; ks < 3; ks++){
    bf16x8 bfr = *(const bf16x8*)(xnF + ((nt * 12 + ks * 4 + q) * 16 + h) * 8);
    #pragma unroll
    for (int mt = 0; mt < 12; mt++){
      bf16x8 afr = *(const bf16x8*)(w1F + (((mh * 12 + mt) * 12 + ks * 4 + q) * 16 + h) * 8);
      acc[mt] = __builtin_amdgcn_mfma_f32_16x16x32_bf16(afr, bfr, acc[mt], 0, 0, 0);
    }
  }
  #pragma unroll
  for (int mt = 0; mt < 12; mt++){
    int o0 = (mh * 12 + mt) * 16 + 4 * q;
    unsigned short pk[4];
    #pragma unroll
    for (int rg = 0; rg < 4; rg++){
      float v = acc[mt][rg];
      pk[rg] = f2bf(0.5f * v * (1.f + erff(v * 0.70710678118654752f)));
    }
    unsigned short* d = hF + ((nt * 48 + (o0 >> 3)) * 16 + h) * 8 + (o0 & 7);
    uint2 pkv; pkv.x = (unsigned)pk[0] | ((unsigned)pk[1] << 16);
    pkv.y = (unsigned)pk[2] | ((unsigned)pk[3] << 16);
    *(uint2*)d = pkv;
  }
  __syncthreads();

  f32x4 acc2[3];
  #pragma unroll
  for (int mt = 0; mt < 3; mt++){
    int o0 = (mh * 3 + mt) * 16 + 4 * q;
    float4 bv = *(const float4*)(b2g + o0);
    acc2[mt][0] = bv.x; acc2[mt][1] = bv.y; acc2[mt][2] = bv.z; acc2[mt][3] = bv.w;
  }
  for (int ks = 0; ks < 12; ks++){
    bf16x8 bfr = *(const bf16x8*)(hF + ((nt * 48 + ks * 4 + q) * 16 + h) * 8);
    #pragma unroll
    for (int mt = 0; mt < 3; mt++){
      bf16x8 afr = *(const bf16x8*)(w2F + (((mh * 3 + mt) * 48 + ks * 4 + q) * 16 + h) * 8);
      acc2[mt] = __builtin_amdgcn_mfma_f32_16x16x32_bf16(afr, bfr, acc2[mt], 0, 0, 0);
    }
  }
  float* orow = io + (row0 + nt * 16 + h) * 96;
  #pragma unroll
  for (int mt = 0; mt < 3; mt++){
    int o0 = (mh * 3 + mt) * 16 + 4 * q;
    float4 cur = *(const float4*)(orow + o0);
    cur.x += acc2[mt][0]; cur.y += acc2[mt][1]; cur.z += acc2[mt][2]; cur.w += acc2[mt][3];
    *(float4*)(orow + o0) = cur;
  }
}

extern "C" void kernel_launch(void* const* d_in, const int* in_sizes, int n_in,
                              void* d_out, int out_size, void* d_ws, size_t ws_size,
                              hipStream_t stream)
{
  const float* x      = (const float*)d_in[0];
  const float* n1w    = (const float*)d_in[1];
  const float* n1b    = (const float*)d_in[2];
  const float* qkvw   = (const float*)d_in[3];
  const float* qkvb   = (const float*)d_in[4];
  const float* rpbtab = (const float*)d_in[5];
  const float* projw  = (const float*)d_in[6];
  const float* projb  = (const float*)d_in[7];
  const float* n2w    = (const float*)d_in[8];
  const float* n2b    = (const float*)d_in[9];
  const float* fc1w   = (const float*)d_in[10];
  const float* fc1b   = (const float*)d_in[11];
  const float* fc2w   = (const float*)d_in[12];
  const float* fc2b   = (const float*)d_in[13];
  float* out = (float*)d_out;

  // workspace (halves): qS 8,429,568 | kS 8,429,568 | vT 8,454,144 | aO 8,429,568 | rpbH 495,616
  unsigned short* qS   = (unsigned short*)d_ws;
  unsigned short* kS   = qS + 8429568;
  unsigned short* vT   = kS + 8429568;
  unsigned short* aO   = vT + 8454144;
  unsigned short* rpbH = aO + 8429568;
  // aliases: wQ in aO (dead until k_attn); w1F/w2F/wP in qS (dead after k_attn)
  unsigned short* wQ  = aO;
  unsigned short* w1F = qS;
  unsigned short* w2F = qS + 36864;
  unsigned short* wP  = qS + 73728;

  k_rpb   <<<dim3(968),  dim3(256), 0, stream>>>(rpbtab, rpbH);
  k_wprep1<<<dim3(108),  dim3(256), 0, stream>>>(qkvw, wQ);
  k_qkv   <<<dim3(512),  dim3(256), 0, stream>>>(x, n1w, n1b, wQ, qkvb, qS, kS, vT);
  k_attn  <<<dim3(1024), dim3(256), 0, stream>>>(qS, kS, vT, rpbH, aO);
  k_wprep2<<<dim3(324),  dim3(256), 0, stream>>>(projw, fc1w, fc2w, w1F, w2F, wP);
  k_proj  <<<dim3(512),  dim3(256), 0, stream>>>(aO, wP, projb, x, out);
  k_mlp   <<<dim3(2744), dim3(256), 0, stream>>>(out, n2w, n2b, w1F, fc1b, w2F, fc2b);
}

// Round 7
// 281.312 us; speedup vs baseline: 4.1237x; 1.0136x over previous
//
#include <hip/hip_runtime.h>

#define NTOK 343
#define NP   352
#define SCALE 0.2041241452319315f
#define LOG2E 1.44269504088896340736f
#define VSTR 360   // VT LDS row stride (halves)
#define PSTR 40    // P buf row stride (halves)

typedef __attribute__((ext_vector_type(8))) short bf16x8;
typedef __attribute__((ext_vector_type(4))) float f32x4;

__device__ __forceinline__ unsigned short f2bf(float f){
  unsigned u = __builtin_bit_cast(unsigned, f);
  u += 0x7fffu + ((u >> 16) & 1u);
  return (unsigned short)(u >> 16);
}
__device__ __forceinline__ float bflo(unsigned u){ return __builtin_bit_cast(float, u << 16); }
__device__ __forceinline__ float bfhi(unsigned u){ return __builtin_bit_cast(float, u & 0xffff0000u); }
__device__ __forceinline__ unsigned pk2(float a, float b){
  unsigned ua = __builtin_bit_cast(unsigned, a) + 0x8000u;
  unsigned ub = __builtin_bit_cast(unsigned, b) + 0x8000u;
  return __builtin_amdgcn_perm(ub, ua, 0x07060302u);
}
__device__ __forceinline__ unsigned pkrn(float a, float b){
  return (unsigned)f2bf(a) | ((unsigned)f2bf(b) << 16);
}
// tanh-form GeLU: 8 VALU ops, max err ~3e-4 (≈ bf16 storage noise here)
__device__ __forceinline__ float gelu_fast(float v){
  float u = v * v;
  float m = v * fmaf(0.044715f, u, 1.0f);
  float t = __builtin_amdgcn_exp2f(m * 2.30211422f);   // exp(2*0.7978845608*m') in log2 domain
  float r = __builtin_amdgcn_rcpf(t + 1.0f);
  return fmaf(-v, r, v);                                // v*(1 - r) = 0.5v(1+tanh(...))
}
__device__ __forceinline__ int region(int g){ return (g < 21) ? 0 : ((g < 25) ? 1 : 2); }

// ---------------- K0: bias table, bf16, log2-domain, per-lane uint4 order ----------------
__global__ __launch_bounds__(256) void k_rpb(const float* __restrict__ tab, unsigned short* __restrict__ rpbH){
  const int bid = blockIdx.x;
  const int qt = bid % 22, t2 = bid / 22, kp = t2 % 11, h = t2 / 11;
  for (int e = threadIdx.x; e < 512; e += 256){
    int lane = e >> 3, slot = e & 7;
    int kth = slot >> 2, reg = slot & 3;
    int n = lane & 15, qd = lane >> 4;
    int i = qt * 16 + n;
    int j = (2 * kp + kth) * 16 + qd * 4 + reg;
    float v;
    if (j >= NTOK) v = -1e30f;
    else if (i >= NTOK) v = 0.f;
    else {
      int r1 = i / 49, rm = i - r1 * 49, r2 = rm / 7, r3 = rm - r2 * 7;
      int j1 = j / 49, jm = j - j1 * 49, j2 = jm / 7, j3 = jm - j2 * 7;
      int idx = 13 * ((r1 - j1) + (r2 - j2) + 12) + (r3 - j3) + 6;
      v = tab[idx * 4 + h] * LOG2E;
    }
    rpbH[(size_t)bid * 512 + e] = f2bf(v);
  }
}

// ---------------- K-wprep1: qkv weights -> A-frag layout (lives in aO region) ----------------
__global__ __launch_bounds__(256) void k_wprep1(const float* __restrict__ qw, unsigned short* __restrict__ wQ){
  int p = blockIdx.x * 256 + threadIdx.x;   // 27648 total
  int e = p & 7, m = (p >> 3) & 15, cell = p >> 7;
  int mt = cell / 12, kq = cell - mt * 12;
  wQ[p] = f2bf(qw[(kq * 8 + e) * 288 + mt * 16 + m]);
}

// ---------------- K-wprep2: proj/fc1/fc2 weights -> A-frag layout (lives in qS) ----------------
__global__ __launch_bounds__(256) void k_wprep2(
    const float* __restrict__ pw, const float* __restrict__ w1g, const float* __restrict__ w2g,
    unsigned short* __restrict__ w1F, unsigned short* __restrict__ w2F, unsigned short* __restrict__ wP)
{
  int p = blockIdx.x * 256 + threadIdx.x;   // 82944 total
  if (p < 36864){
    int e = p & 7, m = (p >> 3) & 15, cell = p >> 7;
    int mt = cell / 12, q = cell - mt * 12;
    w1F[p] = f2bf(w1g[(q * 8 + e) * 384 + mt * 16 + m]);
  } else if (p < 73728){
    int p2 = p - 36864;
    int e = p2 & 7, m = (p2 >> 3) & 15, cell = p2 >> 7;
    int omt = cell / 48, q = cell - omt * 48;
    w2F[p2] = f2bf(w2g[(q * 8 + e) * 96 + omt * 16 + m]);
  } else {
    int p3 = p - 73728;
    int e = p3 & 7, m = (p3 >> 3) & 15, cell = p3 >> 7;
    int mt = cell / 12, kq = cell - mt * 12;
    wP[p3] = f2bf(pw[(kq * 8 + e) * 96 + mt * 16 + m]);
  }
}

// ---------------- K1: MFMA LN1 + shift-gather + QKV GEMM (half-window per block) ----------------
__global__ __launch_bounds__(256, 4) void k_qkv(
    const float* __restrict__ x, const float* __restrict__ n1w, const float* __restrict__ n1b,
    const unsigned short* __restrict__ wQ, const float* __restrict__ qb,
    unsigned short* __restrict__ qS, unsigned short* __restrict__ kS, unsigned short* __restrict__ vT)
{
  __shared__ __align__(16) unsigned short xnF[11 * 12 * 16 * 8];   // 33,792 B
  const int blk = blockIdx.x, w = blk >> 1, half = blk & 1;
  const int b = w >> 6, wl = w & 63;
  const int wx = wl >> 4, wy = (wl >> 2) & 3, wz = wl & 3;
  const int tid = threadIdx.x, lane = tid & 63, wv = tid >> 6;

  const float g1 = n1w[lane], h1 = n1b[lane];
  const float g2 = (lane < 32) ? n1w[64 + lane] : 0.f;
  const float h2 = (lane < 32) ? n1b[64 + lane] : 0.f;
  for (int r = wv; r < 176; r += 4){
    int tl = half * 176 + r;
    int tok = (tl < NTOK) ? tl : NTOK - 1;
    int tx = tok / 49, rm = tok - tx * 49, ty = rm / 7, tz = rm - ty * 7;
    int sx = (wx * 7 + tx + 3) % 28, sy = (wy * 7 + ty + 3) % 28, sz = (wz * 7 + tz + 3) % 28;
    const float* xr = x + ((size_t)b * 21952 + ((sx * 28 + sy) * 28 + sz)) * 96;
    float v1 = xr[lane];
    float v2 = (lane < 32) ? xr[64 + lane] : 0.f;
    float s = v1 + v2, sq = v1 * v1 + v2 * v2;
    #pragma unroll
    for (int off = 32; off; off >>= 1){ s += __shfl_xor(s, off); sq += __shfl_xor(sq, off); }
    float mu = s * (1.f / 96.f);
    float rs = rsqrtf(sq * (1.f / 96.f) - mu * mu + 1e-5f);
    int nt = r >> 4, n = r & 15;
    xnF[((nt * 12 + (lane >> 3)) * 16 + n) * 8 + (lane & 7)] = f2bf((v1 - mu) * rs * g1 + h1);
    if (lane < 32){
      int cc = 64 + lane;
      xnF[((nt * 12 + (cc >> 3)) * 16 + n) * 8 + (cc & 7)] = f2bf((v2 - mu) * rs * g2 + h2);
    }
  }
  __syncthreads();

  const int ln = lane & 15, qd = lane >> 4;
  bf16x8 bfr[3][3];
  int nts[3], toks[3];
  #pragma unroll
  for (int t = 0; t < 3; t++){
    int nt = wv + 4 * t;
    nts[t] = (nt < 11) ? nt : -1;
    int ntc = (nt < 11) ? nt : 0;
    toks[t] = half * 176 + ntc * 16 + ln;
    #pragma unroll
    for (int ks = 0; ks < 3; ks++)
      bfr[t][ks] = *(const bf16x8*)(xnF + ((ntc * 12 + ks * 4 + qd) * 16 + ln) * 8);
  }
  for (int mt = 0; mt < 18; mt++){
    bf16x8 afr[3];
    #pragma unroll
    for (int ks = 0; ks < 3; ks++)
      afr[ks] = *(const bf16x8*)(wQ + ((mt * 12 + ks * 4 + qd) * 16 + ln) * 8);
    f32x4 acc[3];
    #pragma unroll
    for (int t = 0; t < 3; t++){ acc[t][0] = 0.f; acc[t][1] = 0.f; acc[t][2] = 0.f; acc[t][3] = 0.f; }
    #pragma unroll
    for (int ks = 0; ks < 3; ks++)
      #pragma unroll
      for (int t = 0; t < 3; t++)
        acc[t] = __builtin_amdgcn_mfma_f32_16x16x32_bf16(afr[ks], bfr[t][ks], acc[t], 0, 0, 0);
    const int o0 = mt * 16 + 4 * qd;
    float4 bv = *(const float4*)(qb + o0);
    const int s3 = o0 / 96, om = o0 - s3 * 96, hh = om / 24, dd = om - hh * 24;
    if (s3 < 2){
      const float sc = (s3 == 0) ? (SCALE * LOG2E) : 1.f;
      unsigned short* hb = ((s3 == 0) ? qS : kS) + ((size_t)(w * 4 + hh)) * 8232 + dd;
      #pragma unroll
      for (int t = 0; t < 3; t++){
        if (nts[t] < 0 || toks[t] >= NTOK) continue;
        uint2 st;
        st.x = pkrn((acc[t][0] + bv.x) * sc, (acc[t][1] + bv.y) * sc);
        st.y = pkrn((acc[t][2] + bv.z) * sc, (acc[t][3] + bv.w) * sc);
        *(uint2*)(hb + (size_t)toks[t] * 24) = st;
      }
    } else {
      unsigned short* hb = vT + ((size_t)(w * 4 + hh)) * 8256 + (size_t)dd * 344;
      #pragma unroll
      for (int t = 0; t < 3; t++){
        if (nts[t] < 0 || toks[t] >= NTOK) continue;
        hb[0 * 344 + toks[t]] = f2bf(acc[t][0] + bv.x);
        hb[1 * 344 + toks[t]] = f2bf(acc[t][1] + bv.y);
        hb[2 * 344 + toks[t]] = f2bf(acc[t][2] + bv.z);
        hb[3 * 344 + toks[t]] = f2bf(acc[t][3] + bv.w);
      }
    }
  }
}

// ---------------- K2: MFMA attention (per window, head) ----------------
__global__ __launch_bounds__(256, 4) void k_attn(
    const unsigned short* __restrict__ qS, const unsigned short* __restrict__ kS,
    const unsigned short* __restrict__ vT, const unsigned short* __restrict__ rpbH,
    unsigned short* __restrict__ aO)
{
  __shared__ __align__(16) unsigned short VTsh[25 * VSTR];   // 18,000 B (row 24 = ones)
  __shared__ __align__(16) unsigned short Psh[4 * 16 * PSTR];
  __shared__ __align__(8) unsigned char lab8[NP];

  const int blk = blockIdx.x, w = blk >> 2, h = blk & 3;
  const int tid = threadIdx.x, lane = tid & 63, wv = tid >> 6;
  const int ln = lane & 15, qd = lane >> 4;

  {
    const unsigned* vg = (const unsigned*)(vT + (size_t)blk * 8256);
    unsigned* vd = (unsigned*)VTsh;
    for (int i = tid; i < 4128; i += 256){
      int d = i / 172, c = i - d * 172;
      vd[d * 180 + c] = vg[i];
    }
    for (int i = tid; i < 192; i += 256){
      int d = i >> 3, c = i & 7;
      vd[d * 180 + 172 + c] = 0u;
    }
    for (int i = tid; i < 180; i += 256) vd[24 * 180 + i] = 0x3f803f80u;
    const int wl = w & 63, wx = wl >> 4, wy = (wl >> 2) & 3, wz = wl & 3;
    for (int n = tid; n < NP; n += 256){
      int tx = n / 49, nm = n - tx * 49, ty = nm / 7, tz = nm - ty * 7;
      lab8[n] = (n < NTOK) ? (unsigned char)(region(wx*7+tx)*9 + region(wy*7+ty)*3 + region(wz*7+tz)) : (unsigned char)0;
    }
  }
  __syncthreads();

  bf16x8 qf[6];
  int labQ[6], qts[6];
  #pragma unroll
  for (int t = 0; t < 6; t++){
    int qtr = wv + 4 * t;
    bool val = qtr < 22;
    qts[t] = val ? qtr : -1;
    int qt = val ? qtr : 0;
    int query = qt * 16 + ln;
    uint4 qv = *(const uint4*)(qS + (size_t)blk * 8232 + (size_t)query * 24 + qd * 8);
    if (qd == 3){ qv.x = 0; qv.y = 0; qv.z = 0; qv.w = 0; }
    qf[t] = __builtin_bit_cast(bf16x8, qv);
    labQ[t] = lab8[qt * 16 + ln];
  }

  f32x4 accO[6][2];
  #pragma unroll
  for (int t = 0; t < 6; t++)
    #pragma unroll
    for (int d2 = 0; d2 < 2; d2++){ accO[t][d2][0]=0.f; accO[t][d2][1]=0.f; accO[t][d2][2]=0.f; accO[t][d2][3]=0.f; }

  const unsigned short* biasBase = rpbH + (size_t)h * (11 * 22 * 512);
  unsigned short* pb = Psh + wv * 16 * PSTR + ln * PSTR;
  const unsigned short* pr = Psh + wv * 16 * PSTR + ln * PSTR + qd * 8;
  const int vrow1 = (ln < 8) ? (16 + ln) : 24;
  const size_t kbase = (size_t)blk * 8232;

  for (int kp = 0; kp < 11; kp++){
    uint4 kv0 = *(const uint4*)(kS + kbase + (size_t)(kp * 32 + ln) * 24 + qd * 8);
    uint4 kv1 = *(const uint4*)(kS + kbase + (size_t)(kp * 32 + 16 + ln) * 24 + qd * 8);
    bf16x8 kf0 = __builtin_bit_cast(bf16x8, kv0);
    bf16x8 kf1 = __builtin_bit_cast(bf16x8, kv1);
    bf16x8 vf0 = *(const bf16x8*)(VTsh + ln * VSTR + kp * 32 + qd * 8);
    bf16x8 vf1 = *(const bf16x8*)(VTsh + vrow1 * VSTR + kp * 32 + qd * 8);
    const unsigned* l32 = (const unsigned*)lab8;
    unsigned la = l32[kp * 8 + qd];
    unsigned lb = l32[kp * 8 + 4 + qd];
    int kl0[4], kl1[4];
    #pragma unroll
    for (int r = 0; r < 4; r++){ kl0[r] = (la >> (8 * r)) & 255; kl1[r] = (lb >> (8 * r)) & 255; }

    #pragma unroll
    for (int t = 0; t < 6; t++){
      if (qts[t] < 0) continue;
      const int qt = qts[t];
      uint4 bv = *(const uint4*)(biasBase + (((size_t)kp * 22 + qt) * 64 + lane) * 8);
      f32x4 C0, C1;
      C0[0] = bflo(bv.x); C0[1] = bfhi(bv.x); C0[2] = bflo(bv.y); C0[3] = bfhi(bv.y);
      C1[0] = bflo(bv.z); C1[1] = bfhi(bv.z); C1[2] = bflo(bv.w); C1[3] = bfhi(bv.w);
      f32x4 s0 = __builtin_amdgcn_mfma_f32_16x16x32_bf16(kf0, qf[t], C0, 0, 0, 0);
      f32x4 s1 = __builtin_amdgcn_mfma_f32_16x16x32_bf16(kf1, qf[t], C1, 0, 0, 0);
      const int lq = labQ[t];
      float e0[4], e1[4];
      #pragma unroll
      for (int r = 0; r < 4; r++){
        float ev = __builtin_amdgcn_exp2f(s0[r]);
        e0[r] = (kl0[r] == lq) ? ev : 0.f;
      }
      #pragma unroll
      for (int r = 0; r < 4; r++){
        float ev = __builtin_amdgcn_exp2f(s1[r]);
        e1[r] = (kl1[r] == lq) ? ev : 0.f;
      }
      uint2 w0; w0.x = pk2(e0[0], e0[1]); w0.y = pk2(e0[2], e0[3]);
      uint2 w1; w1.x = pk2(e1[0], e1[1]); w1.y = pk2(e1[2], e1[3]);
      *(uint2*)(pb + 4 * qd)      = w0;
      *(uint2*)(pb + 16 + 4 * qd) = w1;
      bf16x8 pf = *(const bf16x8*)pr;
      accO[t][0] = __builtin_amdgcn_mfma_f32_16x16x32_bf16(vf0, pf, accO[t][0], 0, 0, 0);
      accO[t][1] = __builtin_amdgcn_mfma_f32_16x16x32_bf16(vf1, pf, accO[t][1], 0, 0, 0);
    }
  }

  #pragma unroll
  for (int t = 0; t < 6; t++){
    if (qts[t] < 0) continue;
    float ss = __shfl(accO[t][1][0], 32 + ln);
    float inv = 1.f / ss;
    int query = qts[t] * 16 + ln;
    if (query < NTOK){
      unsigned short* dst = aO + (size_t)w * 32928 + (size_t)query * 96 + h * 24;
      uint2 o0;
      o0.x = pkrn(accO[t][0][0] * inv, accO[t][0][1] * inv);
      o0.y = pkrn(accO[t][0][2] * inv, accO[t][0][3] * inv);
      *(uint2*)(dst + 4 * qd) = o0;
      if (qd < 2){
        uint2 o1;
        o1.x = pkrn(accO[t][1][0] * inv, accO[t][1][1] * inv);
        o1.y = pkrn(accO[t][1][2] * inv, accO[t][1][3] * inv);
        *(uint2*)(dst + 16 + 4 * qd) = o1;
      }
    }
  }
}

// ---------------- K3: MFMA proj + window-reverse + un-shift + residual ----------------
__global__ __launch_bounds__(256, 4) void k_proj(
    const unsigned short* __restrict__ aO, const unsigned short* __restrict__ wP,
    const float* __restrict__ pb, const float* __restrict__ x, float* __restrict__ out)
{
  __shared__ __align__(16) unsigned short aF[11 * 12 * 16 * 8];   // 33,792 B
  const int blk = blockIdx.x, w = blk >> 1, half = blk & 1;
  const int b = w >> 6, wl = w & 63;
  const int wx = wl >> 4, wy = (wl >> 2) & 3, wz = wl & 3;
  const int tid = threadIdx.x, lane = tid & 63, wv = tid >> 6;

  for (int i = tid; i < 2112; i += 256){
    int r = i / 12, kq = i - r * 12;
    int tl = half * 176 + r;
    uint4 v;
    if (tl < NTOK) v = *(const uint4*)(aO + (size_t)w * 32928 + (size_t)tl * 96 + kq * 8);
    else { v.x = 0u; v.y = 0u; v.z = 0u; v.w = 0u; }
    int nt = r >> 4, n = r & 15;
    *(uint4*)(aF + ((nt * 12 + kq) * 16 + n) * 8) = v;
  }
  __syncthreads();

  const int ln = lane & 15, qd = lane >> 4;
  bf16x8 bfr[3][3];
  int nts[3]; size_t oi[3]; bool tv[3];
  #pragma unroll
  for (int t = 0; t < 3; t++){
    int nt = wv + 4 * t;
    nts[t] = (nt < 11) ? nt : -1;
    int ntc = (nt < 11) ? nt : 0;
    int tok = half * 176 + ntc * 16 + ln;
    tv[t] = (nts[t] >= 0) && (tok < NTOK);
    int tk = (tok < NTOK) ? tok : 0;
    int tx = tk / 49, rm = tk - tx * 49, ty = rm / 7, tz = rm - ty * 7;
    int sx = (wx * 7 + tx + 3) % 28, sy = (wy * 7 + ty + 3) % 28, sz = (wz * 7 + tz + 3) % 28;
    oi[t] = ((size_t)b * 21952 + ((sx * 28 + sy) * 28 + sz)) * 96;
    #pragma unroll
    for (int ks = 0; ks < 3; ks++)
      bfr[t][ks] = *(const bf16x8*)(aF + ((ntc * 12 + ks * 4 + qd) * 16 + ln) * 8);
  }
  for (int mt = 0; mt < 6; mt++){
    bf16x8 afr[3];
    #pragma unroll
    for (int ks = 0; ks < 3; ks++)
      afr[ks] = *(const bf16x8*)(wP + ((mt * 12 + ks * 4 + qd) * 16 + ln) * 8);
    f32x4 acc[3];
    #pragma unroll
    for (int t = 0; t < 3; t++){ acc[t][0] = 0.f; acc[t][1] = 0.f; acc[t][2] = 0.f; acc[t][3] = 0.f; }
    #pragma unroll
    for (int ks = 0; ks < 3; ks++)
      #pragma unroll
      for (int t = 0; t < 3; t++)
        acc[t] = __builtin_amdgcn_mfma_f32_16x16x32_bf16(afr[ks], bfr[t][ks], acc[t], 0, 0, 0);
    const int c0 = mt * 16 + 4 * qd;
    float4 bv = *(const float4*)(pb + c0);
    #pragma unroll
    for (int t = 0; t < 3; t++){
      if (!tv[t]) continue;
      float4 cur = *(const float4*)(x + oi[t] + c0);
      float4 o;
      o.x = acc[t][0] + bv.x + cur.x;
      o.y = acc[t][1] + bv.y + cur.y;
      o.z = acc[t][2] + bv.z + cur.z;
      o.w = acc[t][3] + bv.w + cur.w;
      *(float4*)(out + oi[t] + c0) = o;
    }
  }
}

// ---------------- K4: MFMA MLP (64 rows, 512 thr): LN2 + fc1 + fastGeLU + fc2 + residual ----------
__global__ __launch_bounds__(512, 2) void k_mlp(
    float* __restrict__ io, const float* __restrict__ n2w, const float* __restrict__ n2b,
    const unsigned short* __restrict__ w1F, const float* __restrict__ b1g,
    const unsigned short* __restrict__ w2F, const float* __restrict__ b2g)
{
  __shared__ __align__(16) unsigned short xnF[4 * 12 * 16 * 8];   // 12,288 B
  __shared__ __align__(16) unsigned short hF[4 * 48 * 16 * 8];    // 49,152 B
  const int tid = threadIdx.x, lane = tid & 63, wv = tid >> 6;    // 8 waves
  const size_t row0 = (size_t)blockIdx.x * 64;

  const float g1 = n2w[lane], c1 = n2b[lane];
  const float g2 = (lane < 32) ? n2w[64 + lane] : 0.f;
  const float c2 = (lane < 32) ? n2b[64 + lane] : 0.f;
  for (int r = wv; r < 64; r += 8){
    const float* xr = io + (row0 + r) * 96;
    float v1 = xr[lane], v2 = (lane < 32) ? xr[64 + lane] : 0.f;
    float s = v1 + v2, sq = v1 * v1 + v2 * v2;
    #pragma unroll
    for (int off = 32; off; off >>= 1){ s += __shfl_xor(s, off); sq += __shfl_xor(sq, off); }
    float mu = s * (1.f / 96.f);
    float rs = rsqrtf(sq * (1.f / 96.f) - mu * mu + 1e-5f);
    int nt = r >> 4, n = r & 15;
    xnF[((nt * 12 + (lane >> 3)) * 16 + n) * 8 + (lane & 7)] = f2bf((v1 - mu) * rs * g1 + c1);
    if (lane < 32){
      int cc = 64 + lane;
      xnF[((nt * 12 + (cc >> 3)) * 16 + n) * 8 + (cc & 7)] = f2bf((v2 - mu) * rs * g2 + c2);
    }
  }
  __syncthreads();

  const int h = lane & 15, q = lane >> 4;
  const int nt = wv & 3, mh = wv >> 2;      // 4 token tiles, 2 M-halves

  // ---- fc1: 12 m-tiles (192 hidden ch) x 16 tokens, K=96 ----
  f32x4 acc[12];
  #pragma unroll
  for (int mt = 0; mt < 12; mt++){
    int o0 = (mh * 12 + mt) * 16 + 4 * q;
    float4 bv = *(const float4*)(b1g + o0);
    acc[mt][0] = bv.x; acc[mt][1] = bv.y; acc[mt][2] = bv.z; acc[mt][3] = bv.w;
  }
  for (int ks = 0; ks < 3; ks++){
    bf16x8 bfr = *(const bf16x8*)(xnF + ((nt * 12 + ks * 4 + q) * 16 + h) * 8);
    #pragma unroll
    for (int mt = 0; mt < 12; mt++){
      bf16x8 afr = *(const bf16x8*)(w1F + (((mh * 12 + mt) * 12 + ks * 4 + q) * 16 + h) * 8);
      acc[mt] = __builtin_amdgcn_mfma_f32_16x16x32_bf16(afr, bfr, acc[mt], 0, 0, 0);
    }
  }
  // fast GeLU + pack to fc2-B-fragment layout
  #pragma unroll
  for (int mt = 0; mt < 12; mt++){
    int o0 = (mh * 12 + mt) * 16 + 4 * q;
    float g0 = gelu_fast(acc[mt][0]), g1v = gelu_fast(acc[mt][1]);
    float g2v = gelu_fast(acc[mt][2]), g3 = gelu_fast(acc[mt][3]);
    unsigned short* d = hF + ((nt * 48 + (o0 >> 3)) * 16 + h) * 8 + (o0 & 7);
    uint2 pkv; pkv.x = pk2(g0, g1v); pkv.y = pk2(g2v, g3);
    *(uint2*)d = pkv;
  }
  __syncthreads();

  // ---- fc2: 3 m-tiles (48 out ch) x 16 tokens, K=384 ----
  f32x4 acc2[3];
  #pragma unroll
  for (int mt = 0; mt < 3; mt++){
    int o0 = (mh * 3 + mt) * 16 + 4 * q;
    float4 bv = *(const float4*)(b2g + o0);
    acc2[mt][0] = bv.x; acc2[mt][1] = bv.y; acc2[mt][2] = bv.z; acc2[mt][3] = bv.w;
  }
  for (int ks = 0; ks < 12; ks++){
    bf16x8 bfr = *(const bf16x8*)(hF + ((nt * 48 + ks * 4 + q) * 16 + h) * 8);
    #pragma unroll
    for (int mt = 0; mt < 3; mt++){
      bf16x8 afr = *(const bf16x8*)(w2F + (((mh * 3 + mt) * 48 + ks * 4 + q) * 16 + h) * 8);
      acc2[mt] = __builtin_amdgcn_mfma_f32_16x16x32_bf16(afr, bfr, acc2[mt], 0, 0, 0);
    }
  }
  float* orow = io + (row0 + nt * 16 + h) * 96;
  #pragma unroll
  for (int mt = 0; mt < 3; mt++){
    int o0 = (mh * 3 + mt) * 16 + 4 * q;
    float4 cur = *(const float4*)(orow + o0);
    cur.x += acc2[mt][0]; cur.y += acc2[mt][1]; cur.z += acc2[mt][2]; cur.w += acc2[mt][3];
    *(float4*)(orow + o0) = cur;
  }
}

extern "C" void kernel_launch(void* const* d_in, const int* in_sizes, int n_in,
                              void* d_out, int out_size, void* d_ws, size_t ws_size,
                              hipStream_t stream)
{
  const float* x      = (const float*)d_in[0];
  const float* n1w    = (const float*)d_in[1];
  const float* n1b    = (const float*)d_in[2];
  const float* qkvw   = (const float*)d_in[3];
  const float* qkvb   = (const float*)d_in[4];
  const float* rpbtab = (const float*)d_in[5];
  const float* projw  = (const float*)d_in[6];
  const float* projb  = (const float*)d_in[7];
  const float* n2w    = (const float*)d_in[8];
  const float* n2b    = (const float*)d_in[9];
  const float* fc1w   = (const float*)d_in[10];
  const float* fc1b   = (const float*)d_in[11];
  const float* fc2w   = (const float*)d_in[12];
  const float* fc2b   = (const float*)d_in[13];
  float* out = (float*)d_out;

  // workspace (halves): qS 8,429,568 | kS 8,429,568 | vT 8,454,144 | aO 8,429,568 | rpbH 495,616
  unsigned short* qS   = (unsigned short*)d_ws;
  unsigned short* kS   = qS + 8429568;
  unsigned short* vT   = kS + 8429568;
  unsigned short* aO   = vT + 8454144;
  unsigned short* rpbH = aO + 8429568;
  unsigned short* wQ  = aO;
  unsigned short* w1F = qS;
  unsigned short* w2F = qS + 36864;
  unsigned short* wP  = qS + 73728;

  k_rpb   <<<dim3(968),  dim3(256), 0, stream>>>(rpbtab, rpbH);
  k_wprep1<<<dim3(108),  dim3(256), 0, stream>>>(qkvw, wQ);
  k_qkv   <<<dim3(512),  dim3(256), 0, stream>>>(x, n1w, n1b, wQ, qkvb, qS, kS, vT);
  k_attn  <<<dim3(1024), dim3(256), 0, stream>>>(qS, kS, vT, rpbH, aO);
  k_wprep2<<<dim3(324),  dim3(256), 0, stream>>>(projw, fc1w, fc2w, w1F, w2F, wP);
  k_proj  <<<dim3(512),  dim3(256), 0, stream>>>(aO, wP, projb, x, out);
  k_mlp   <<<dim3(1372), dim3(512), 0, stream>>>(out, n2w, n2b, w1F, fc1b, w2F, fc2b);
}